// Round 1
// baseline (168.359 us; speedup 1.0000x reference)
//
#include <hip/hip_runtime.h>
#include <math.h>

#define B_ 4
#define C_ 64
#define N_ 4096

typedef unsigned short u16;
typedef __attribute__((ext_vector_type(8))) short bf16x8;
typedef __attribute__((ext_vector_type(4))) float f32x4;

__device__ __forceinline__ u16 f2bf(float f) {
    unsigned u = __float_as_uint(f);
    u += 0x7fff + ((u >> 16) & 1);
    return (u16)(u >> 16);
}
__device__ __forceinline__ float bf2f(u16 h) {
    return __uint_as_float(((unsigned)h) << 16);
}

// ---------------- Kernel 1: GroupNorm partial reduction (deterministic split-K) ----------------
// grid 256: bg = blockIdx>>3 (0..31), chunk = blockIdx&7. Each block reduces 4096 contiguous floats.
__global__ __launch_bounds__(256) void gn_reduce(const float* __restrict__ x,
                                                 float* __restrict__ partials) {
    int bg = blockIdx.x >> 3, chunk = blockIdx.x & 7;
    const float4* xv = (const float4*)(x + (size_t)bg * 32768 + (size_t)chunk * 4096);
    float s = 0.f, ss = 0.f;
    #pragma unroll
    for (int k = 0; k < 4; k++) {
        float4 v = xv[threadIdx.x + 256 * k];
        s += v.x + v.y + v.z + v.w;
        ss += v.x * v.x + v.y * v.y + v.z * v.z + v.w * v.w;
    }
    #pragma unroll
    for (int off = 1; off < 64; off <<= 1) {
        s += __shfl_xor(s, off);
        ss += __shfl_xor(ss, off);
    }
    __shared__ float red[2][4];
    int w = threadIdx.x >> 6;
    if ((threadIdx.x & 63) == 0) { red[0][w] = s; red[1][w] = ss; }
    __syncthreads();
    if (threadIdx.x == 0) {
        s = red[0][0] + red[0][1] + red[0][2] + red[0][3];
        ss = red[1][0] + red[1][1] + red[1][2] + red[1][3];
        partials[bg * 16 + chunk * 2] = s;
        partials[bg * 16 + chunk * 2 + 1] = ss;
    }
}

// ---------------- Kernel 2: GroupNorm apply -> xn bf16 [B, N, C] ----------------
// grid 256: bg = blockIdx>>3, chunk = blockIdx&7 covers 512 pixels.
__global__ __launch_bounds__(256) void gn_apply(const float* __restrict__ x,
                                                const float* __restrict__ gamma,
                                                const float* __restrict__ beta,
                                                const float* __restrict__ partials,
                                                u16* __restrict__ xn) {
    int bg = blockIdx.x >> 3, chunk = blockIdx.x & 7;
    int b = bg >> 3, g = bg & 7;
    float s = 0.f, ss = 0.f;
    #pragma unroll
    for (int i = 0; i < 8; i++) {
        s += partials[bg * 16 + i * 2];
        ss += partials[bg * 16 + i * 2 + 1];
    }
    float mean = s * (1.f / 32768.f);
    float var = ss * (1.f / 32768.f) - mean * mean;
    float rstd = rsqrtf(var + 1e-5f);
    float ga[8], bb[8];
    #pragma unroll
    for (int j = 0; j < 8; j++) {
        float gm = gamma[g * 8 + j] * rstd;
        ga[j] = gm;
        bb[j] = beta[g * 8 + j] - mean * gm;
    }
    const float* xp = x + (size_t)(b * C_ + g * 8) * N_;
    u16* outp = xn + (size_t)b * N_ * C_ + g * 8;
    int n0 = chunk * 512;
    for (int it = 0; it < 2; it++) {
        int n = n0 + threadIdx.x + it * 256;
        u16 pk[8];
        #pragma unroll
        for (int j = 0; j < 8; j++) {
            float v = xp[j * N_ + n];
            pk[j] = f2bf(v * ga[j] + bb[j]);
        }
        *(uint4*)(outp + (size_t)n * C_) = *(uint4*)pk;
    }
}

// ---------------- Kernel 3: QKV projections ----------------
// Q,K -> [B,N,C] bf16 (Q pre-scaled by 1/8); V -> [B,C,N] bf16 (transposed).
__global__ __launch_bounds__(256) void qkv_kernel(
    const u16* __restrict__ xn,
    const float* __restrict__ Wq, const float* __restrict__ bq,
    const float* __restrict__ Wk, const float* __restrict__ bk,
    const float* __restrict__ Wv, const float* __restrict__ bv,
    u16* __restrict__ Qo, u16* __restrict__ Ko, u16* __restrict__ Vt) {
    __shared__ __align__(16) u16 xt[64][72];
    __shared__ __align__(16) float wl[64][68];
    const int b = blockIdx.x >> 6;
    const int nt = blockIdx.x & 63;
    const int tid = threadIdx.x;

    {   // stage xn tile (bf16), rows = pixels
        const uint4* src = (const uint4*)(xn + ((size_t)(b * N_ + nt * 64)) * C_);
        #pragma unroll
        for (int k = 0; k < 2; k++) {
            int i = tid + k * 256;
            int p = i >> 3, c8 = i & 7;
            *(uint4*)&xt[p][c8 * 8] = src[i];
        }
    }

    const int p = tid >> 2, qd = tid & 3;
    const int n = nt * 64 + p;
    const float* Ws[3] = {Wq, Wk, Wv};
    const float* bs[3] = {bq, bk, bv};

    #pragma unroll
    for (int set = 0; set < 3; set++) {
        __syncthreads();  // xt ready (set0) / previous set's wl readers done
        #pragma unroll
        for (int k = 0; k < 4; k++) {
            int i = tid + k * 256;
            *(float4*)&wl[i >> 4][(i & 15) * 4] = ((const float4*)Ws[set])[i];
        }
        __syncthreads();
        float acc[16];
        #pragma unroll
        for (int j = 0; j < 16; j++) acc[j] = bs[set][qd + 4 * j];
        #pragma unroll
        for (int c8 = 0; c8 < 8; c8++) {
            u16 xv[8];
            *(uint4*)xv = *(uint4*)&xt[p][c8 * 8];
            float xf[8];
            #pragma unroll
            for (int e = 0; e < 8; e++) xf[e] = bf2f(xv[e]);
            #pragma unroll
            for (int j = 0; j < 16; j++) {
                int o = qd + 4 * j;
                float4 w0 = *(float4*)&wl[o][c8 * 8];
                float4 w1 = *(float4*)&wl[o][c8 * 8 + 4];
                acc[j] += xf[0] * w0.x + xf[1] * w0.y + xf[2] * w0.z + xf[3] * w0.w
                        + xf[4] * w1.x + xf[5] * w1.y + xf[6] * w1.z + xf[7] * w1.w;
            }
        }
        if (set == 0) {
            u16* dst = Qo + ((size_t)(b * N_) + n) * C_;
            #pragma unroll
            for (int j = 0; j < 16; j++) dst[qd + 4 * j] = f2bf(acc[j] * 0.125f);
        } else if (set == 1) {
            u16* dst = Ko + ((size_t)(b * N_) + n) * C_;
            #pragma unroll
            for (int j = 0; j < 16; j++) dst[qd + 4 * j] = f2bf(acc[j]);
        } else {
            #pragma unroll
            for (int j = 0; j < 16; j++)
                Vt[((size_t)(b * C_) + qd + 4 * j) * N_ + n] = f2bf(acc[j]);
        }
    }
}

// ---------------- Kernel 4: flash attention ----------------
// grid 256 = B * N/64. 4 waves; wave w owns rows 16w..16w+15 of the Q tile.
// mfma_f32_16x16x32_bf16: A lane l -> A[l&15][(l>>4)*8+j]; B lane l -> B[(l>>4)*8+j][l&15];
// D lane l -> D[(l>>4)*4+r][l&15]  (guide §3, m89-verified).
__global__ __launch_bounds__(256) void flash_kernel(
    const u16* __restrict__ Qg, const u16* __restrict__ Kg,
    const u16* __restrict__ Vg, u16* __restrict__ Og) {
    __shared__ __align__(16) u16 Qs[64][72];
    __shared__ __align__(16) u16 Ks[64][72];
    __shared__ __align__(16) u16 Vs[64][72];   // [channel][key]
    __shared__ __align__(16) u16 Ps[4][16][72];

    const int b = blockIdx.x >> 6;
    const int qt = blockIdx.x & 63;
    const int tid = threadIdx.x;
    const int w = tid >> 6, lane = tid & 63;
    const int lr = lane & 15, lg = lane >> 4;

    {   // stage Q tile
        int row = tid >> 2, c0 = (tid & 3) * 16;
        const uint4* src = (const uint4*)(Qg + ((size_t)(b * N_ + qt * 64 + row)) * C_ + c0);
        *(uint4*)&Qs[row][c0] = src[0];
        *(uint4*)&Qs[row][c0 + 8] = src[1];
    }
    __syncthreads();
    bf16x8 aq0 = *(bf16x8*)&Qs[w * 16 + lr][lg * 8];
    bf16x8 aq1 = *(bf16x8*)&Qs[w * 16 + lr][32 + lg * 8];

    f32x4 zz = {0.f, 0.f, 0.f, 0.f};
    f32x4 o[4];
    float m[4], l[4];
    #pragma unroll
    for (int r = 0; r < 4; r++) { m[r] = -INFINITY; l[r] = 0.f; o[r] = zz; }

    for (int kt = 0; kt < 64; kt++) {
        {   // stage K tile (rows = keys) and V tile (rows = channels)
            int row = tid >> 2, c0 = (tid & 3) * 16;
            const uint4* ks = (const uint4*)(Kg + ((size_t)(b * N_ + kt * 64 + row)) * C_ + c0);
            uint4 k0 = ks[0], k1 = ks[1];
            const uint4* vs = (const uint4*)(Vg + ((size_t)(b * C_ + row)) * N_ + kt * 64 + c0);
            uint4 v0 = vs[0], v1 = vs[1];
            *(uint4*)&Ks[row][c0] = k0;
            *(uint4*)&Ks[row][c0 + 8] = k1;
            *(uint4*)&Vs[row][c0] = v0;
            *(uint4*)&Vs[row][c0 + 8] = v1;
        }
        __syncthreads();

        f32x4 s[4];
        #pragma unroll
        for (int ct = 0; ct < 4; ct++) {
            bf16x8 b0 = *(bf16x8*)&Ks[ct * 16 + lr][lg * 8];
            bf16x8 b1 = *(bf16x8*)&Ks[ct * 16 + lr][32 + lg * 8];
            f32x4 acc = zz;
            acc = __builtin_amdgcn_mfma_f32_16x16x32_bf16(aq0, b0, acc, 0, 0, 0);
            acc = __builtin_amdgcn_mfma_f32_16x16x32_bf16(aq1, b1, acc, 0, 0, 0);
            s[ct] = acc;
        }

        float pv[4][4];
        #pragma unroll
        for (int r = 0; r < 4; r++) {
            float mx = fmaxf(fmaxf(s[0][r], s[1][r]), fmaxf(s[2][r], s[3][r]));
            #pragma unroll
            for (int off = 1; off < 16; off <<= 1) mx = fmaxf(mx, __shfl_xor(mx, off));
            float mnew = fmaxf(m[r], mx);
            float alpha = __expf(m[r] - mnew);
            m[r] = mnew;
            float ps = 0.f;
            #pragma unroll
            for (int ct = 0; ct < 4; ct++) {
                float p = __expf(s[ct][r] - mnew);
                pv[ct][r] = p;
                ps += p;
            }
            #pragma unroll
            for (int off = 1; off < 16; off <<= 1) ps += __shfl_xor(ps, off);
            l[r] = l[r] * alpha + ps;
            #pragma unroll
            for (int ct = 0; ct < 4; ct++) o[ct][r] *= alpha;
        }

        #pragma unroll
        for (int r = 0; r < 4; r++)
            #pragma unroll
            for (int ct = 0; ct < 4; ct++)
                Ps[w][lg * 4 + r][ct * 16 + lr] = f2bf(pv[ct][r]);
        asm volatile("s_waitcnt lgkmcnt(0)" ::: "memory");  // wave's P writes visible to its own frag reads

        #pragma unroll
        for (int kk = 0; kk < 2; kk++) {
            bf16x8 pa = *(bf16x8*)&Ps[w][lr][kk * 32 + lg * 8];
            #pragma unroll
            for (int ct = 0; ct < 4; ct++) {
                bf16x8 bv = *(bf16x8*)&Vs[ct * 16 + lr][kk * 32 + lg * 8];
                o[ct] = __builtin_amdgcn_mfma_f32_16x16x32_bf16(pa, bv, o[ct], 0, 0, 0);
            }
        }
        __syncthreads();  // all waves done reading K/V before next stage
    }

    #pragma unroll
    for (int r = 0; r < 4; r++) {
        float inv = 1.f / l[r];
        #pragma unroll
        for (int ct = 0; ct < 4; ct++) o[ct][r] *= inv;
    }
    u16* op = Og + ((size_t)(b * N_ + qt * 64 + w * 16)) * C_;
    #pragma unroll
    for (int r = 0; r < 4; r++)
        #pragma unroll
        for (int ct = 0; ct < 4; ct++)
            op[(lg * 4 + r) * C_ + ct * 16 + lr] = f2bf(o[ct][r]);
}

// ---------------- Kernel 5: output projection + residual ----------------
__global__ __launch_bounds__(256) void proj_kernel(
    const u16* __restrict__ Og, const float* __restrict__ Wp,
    const float* __restrict__ bp, const float* __restrict__ x,
    float* __restrict__ out) {
    __shared__ __align__(16) float ot[64][68];
    __shared__ __align__(16) float wpl[64][68];
    const int b = blockIdx.x >> 6;
    const int nt = blockIdx.x & 63;
    const int tid = threadIdx.x;

    #pragma unroll
    for (int k = 0; k < 4; k++) {
        int i = tid + k * 256;
        float4 v = ((const float4*)Wp)[i];
        *(float4*)&wpl[i >> 4][(i & 15) * 4] = v;
    }
    {
        const uint4* src = (const uint4*)(Og + ((size_t)(b * N_ + nt * 64)) * C_);
        #pragma unroll
        for (int k = 0; k < 2; k++) {
            int i = tid + k * 256;
            int p = i >> 3, c8 = i & 7;
            u16 tmp[8];
            *(uint4*)tmp = src[i];
            #pragma unroll
            for (int j = 0; j < 8; j++) ot[p][c8 * 8 + j] = bf2f(tmp[j]);
        }
    }
    __syncthreads();

    const int co = tid >> 2, ng = tid & 3;
    float acc[16];
    #pragma unroll
    for (int p = 0; p < 16; p++) acc[p] = 0.f;
    #pragma unroll
    for (int c4 = 0; c4 < 16; c4++) {
        float4 w4 = *(float4*)&wpl[co][c4 * 4];
        #pragma unroll
        for (int p = 0; p < 16; p++) {
            float4 o4 = *(float4*)&ot[ng + p * 4][c4 * 4];
            acc[p] += w4.x * o4.x + w4.y * o4.y + w4.z * o4.z + w4.w * o4.w;
        }
    }
    float bias = bp[co];
    const size_t base = (size_t)(b * C_ + co) * N_ + (size_t)nt * 64;
    #pragma unroll
    for (int p = 0; p < 16; p++) {
        int n = ng + p * 4;
        out[base + n] = x[base + n] + bias + acc[p];
    }
}

extern "C" void kernel_launch(void* const* d_in, const int* in_sizes, int n_in,
                              void* d_out, int out_size, void* d_ws, size_t ws_size,
                              hipStream_t stream) {
    const float* x     = (const float*)d_in[0];
    const float* gamma = (const float*)d_in[1];
    const float* beta  = (const float*)d_in[2];
    const float* Wq    = (const float*)d_in[3];
    const float* bq    = (const float*)d_in[4];
    const float* Wk    = (const float*)d_in[5];
    const float* bk    = (const float*)d_in[6];
    const float* Wv    = (const float*)d_in[7];
    const float* bv    = (const float*)d_in[8];
    const float* Wp    = (const float*)d_in[9];
    const float* bp    = (const float*)d_in[10];
    float* out = (float*)d_out;

    const size_t elems = (size_t)B_ * N_ * C_;  // 1M
    float* partials = (float*)d_ws;             // 512 floats
    u16* xn = (u16*)((char*)d_ws + 4096);
    u16* Qb = xn + elems;
    u16* Kb = Qb + elems;
    u16* Vt = Kb + elems;
    u16* Ob = Vt + elems;

    gn_reduce<<<256, 256, 0, stream>>>(x, partials);
    gn_apply<<<256, 256, 0, stream>>>(x, gamma, beta, partials, xn);
    qkv_kernel<<<256, 256, 0, stream>>>(xn, Wq, bq, Wk, bk, Wv, bv, Qb, Kb, Vt);
    flash_kernel<<<256, 256, 0, stream>>>(Qb, Kb, Vt, Ob);
    proj_kernel<<<256, 256, 0, stream>>>(Ob, Wp, bp, x, out);
}

// Round 2
// 127.769 us; speedup vs baseline: 1.3177x; 1.3177x over previous
//
#include <hip/hip_runtime.h>
#include <math.h>

#define B_ 4
#define C_ 64
#define N_ 4096

typedef unsigned short u16;
typedef __attribute__((ext_vector_type(8))) short bf16x8;
typedef __attribute__((ext_vector_type(4))) float f32x4;

__device__ __forceinline__ u16 f2bf(float f) {
    unsigned u = __float_as_uint(f);
    u += 0x7fff + ((u >> 16) & 1);
    return (u16)(u >> 16);
}
__device__ __forceinline__ float bf2f(u16 h) {
    return __uint_as_float(((unsigned)h) << 16);
}

// ---------------- Kernel 1: GroupNorm partial reduction (deterministic split-K) ----------------
__global__ __launch_bounds__(256) void gn_reduce(const float* __restrict__ x,
                                                 float* __restrict__ partials) {
    int bg = blockIdx.x >> 3, chunk = blockIdx.x & 7;
    const float4* xv = (const float4*)(x + (size_t)bg * 32768 + (size_t)chunk * 4096);
    float s = 0.f, ss = 0.f;
    #pragma unroll
    for (int k = 0; k < 4; k++) {
        float4 v = xv[threadIdx.x + 256 * k];
        s += v.x + v.y + v.z + v.w;
        ss += v.x * v.x + v.y * v.y + v.z * v.z + v.w * v.w;
    }
    #pragma unroll
    for (int off = 1; off < 64; off <<= 1) {
        s += __shfl_xor(s, off);
        ss += __shfl_xor(ss, off);
    }
    __shared__ float red[2][4];
    int w = threadIdx.x >> 6;
    if ((threadIdx.x & 63) == 0) { red[0][w] = s; red[1][w] = ss; }
    __syncthreads();
    if (threadIdx.x == 0) {
        s = red[0][0] + red[0][1] + red[0][2] + red[0][3];
        ss = red[1][0] + red[1][1] + red[1][2] + red[1][3];
        partials[bg * 16 + chunk * 2] = s;
        partials[bg * 16 + chunk * 2 + 1] = ss;
    }
}

// ---------------- Kernel 2: GroupNorm apply -> xn bf16 [B, N, C] ----------------
__global__ __launch_bounds__(256) void gn_apply(const float* __restrict__ x,
                                                const float* __restrict__ gamma,
                                                const float* __restrict__ beta,
                                                const float* __restrict__ partials,
                                                u16* __restrict__ xn) {
    int bg = blockIdx.x >> 3, chunk = blockIdx.x & 7;
    int b = bg >> 3, g = bg & 7;
    float s = 0.f, ss = 0.f;
    #pragma unroll
    for (int i = 0; i < 8; i++) {
        s += partials[bg * 16 + i * 2];
        ss += partials[bg * 16 + i * 2 + 1];
    }
    float mean = s * (1.f / 32768.f);
    float var = ss * (1.f / 32768.f) - mean * mean;
    float rstd = rsqrtf(var + 1e-5f);
    float ga[8], bb[8];
    #pragma unroll
    for (int j = 0; j < 8; j++) {
        float gm = gamma[g * 8 + j] * rstd;
        ga[j] = gm;
        bb[j] = beta[g * 8 + j] - mean * gm;
    }
    const float* xp = x + (size_t)(b * C_ + g * 8) * N_;
    u16* outp = xn + (size_t)b * N_ * C_ + g * 8;
    int n0 = chunk * 512;
    for (int it = 0; it < 2; it++) {
        int n = n0 + threadIdx.x + it * 256;
        u16 pk[8];
        #pragma unroll
        for (int j = 0; j < 8; j++) {
            float v = xp[j * N_ + n];
            pk[j] = f2bf(v * ga[j] + bb[j]);
        }
        *(uint4*)(outp + (size_t)n * C_) = *(uint4*)pk;
    }
}

// ---------------- Kernel 3: QKV projections ----------------
// Q,K -> [B,N,C] bf16 (Q pre-scaled by 0.125*log2(e) for exp2-domain softmax);
// V -> [B,C,N] bf16 (transposed).
__global__ __launch_bounds__(256) void qkv_kernel(
    const u16* __restrict__ xn,
    const float* __restrict__ Wq, const float* __restrict__ bq,
    const float* __restrict__ Wk, const float* __restrict__ bk,
    const float* __restrict__ Wv, const float* __restrict__ bv,
    u16* __restrict__ Qo, u16* __restrict__ Ko, u16* __restrict__ Vt) {
    __shared__ __align__(16) u16 xt[64][72];
    __shared__ __align__(16) float wl[64][68];
    const int b = blockIdx.x >> 6;
    const int nt = blockIdx.x & 63;
    const int tid = threadIdx.x;

    {   // stage xn tile (bf16), rows = pixels
        const uint4* src = (const uint4*)(xn + ((size_t)(b * N_ + nt * 64)) * C_);
        #pragma unroll
        for (int k = 0; k < 2; k++) {
            int i = tid + k * 256;
            int p = i >> 3, c8 = i & 7;
            *(uint4*)&xt[p][c8 * 8] = src[i];
        }
    }

    const int p = tid >> 2, qd = tid & 3;
    const int n = nt * 64 + p;
    const float* Ws[3] = {Wq, Wk, Wv};
    const float* bs[3] = {bq, bk, bv};

    #pragma unroll
    for (int set = 0; set < 3; set++) {
        __syncthreads();
        #pragma unroll
        for (int k = 0; k < 4; k++) {
            int i = tid + k * 256;
            *(float4*)&wl[i >> 4][(i & 15) * 4] = ((const float4*)Ws[set])[i];
        }
        __syncthreads();
        float acc[16];
        #pragma unroll
        for (int j = 0; j < 16; j++) acc[j] = bs[set][qd + 4 * j];
        #pragma unroll
        for (int c8 = 0; c8 < 8; c8++) {
            u16 xv[8];
            *(uint4*)xv = *(uint4*)&xt[p][c8 * 8];
            float xf[8];
            #pragma unroll
            for (int e = 0; e < 8; e++) xf[e] = bf2f(xv[e]);
            #pragma unroll
            for (int j = 0; j < 16; j++) {
                int o = qd + 4 * j;
                float4 w0 = *(float4*)&wl[o][c8 * 8];
                float4 w1 = *(float4*)&wl[o][c8 * 8 + 4];
                acc[j] += xf[0] * w0.x + xf[1] * w0.y + xf[2] * w0.z + xf[3] * w0.w
                        + xf[4] * w1.x + xf[5] * w1.y + xf[6] * w1.z + xf[7] * w1.w;
            }
        }
        if (set == 0) {
            u16* dst = Qo + ((size_t)(b * N_) + n) * C_;
            #pragma unroll
            for (int j = 0; j < 16; j++) dst[qd + 4 * j] = f2bf(acc[j] * 0.18033688f);
        } else if (set == 1) {
            u16* dst = Ko + ((size_t)(b * N_) + n) * C_;
            #pragma unroll
            for (int j = 0; j < 16; j++) dst[qd + 4 * j] = f2bf(acc[j]);
        } else {
            #pragma unroll
            for (int j = 0; j < 16; j++)
                Vt[((size_t)(b * C_) + qd + 4 * j) * N_ + n] = f2bf(acc[j]);
        }
    }
}

// ---------------- Kernel 4: flash attention, KV-split x2, pipelined, swizzled ----------------
// grid 512 = B * 64 qtiles * 2 splits. 4 waves; wave w owns q rows 16w..16w+15.
// LDS XOR swizzle: element at [row][cb] stored at [row][cb ^ ((row&7)<<4)] (byte addr).
__global__ __launch_bounds__(256) void flash_kernel(
    const u16* __restrict__ Qg, const u16* __restrict__ Kg,
    const u16* __restrict__ Vg, u16* __restrict__ Opart, float* __restrict__ ml) {
    __shared__ __align__(16) u16 Ks[2][4096];
    __shared__ __align__(16) u16 Vs[2][4096];
    __shared__ __align__(16) u16 Ps[4][1024];

    const int sp = blockIdx.x & 1;
    const int qt = (blockIdx.x >> 1) & 63;
    const int b  = blockIdx.x >> 7;
    const int tid = threadIdx.x;
    const int w = tid >> 6, lane = tid & 63;
    const int lr = lane & 15, lg = lane >> 4;

    // Q fragments directly from global (row 128B-aligned, 16B chunks)
    const u16* qrow = Qg + ((size_t)(b * N_ + qt * 64 + w * 16 + lr)) * C_;
    bf16x8 aq0 = *(const bf16x8*)(qrow + lg * 8);
    bf16x8 aq1 = *(const bf16x8*)(qrow + 32 + lg * 8);

    // staging geometry: thread covers 32B of row (tid>>2) at byte col (tid&3)*32
    const int srow = tid >> 2;
    const int scb  = (tid & 3) * 32;
    const char* Kbase = (const char*)(Kg + (size_t)b * N_ * C_) + (size_t)srow * 128 + scb;
    const char* Vbase = (const char*)(Vg + (size_t)b * C_ * N_) + (size_t)srow * (N_ * 2) + scb;
    const int se0 = srow * 64 + (((scb)      ^ ((srow & 7) << 4)) >> 1);
    const int se1 = srow * 64 + (((scb + 16) ^ ((srow & 7) << 4)) >> 1);

    // swizzled fragment-read element offsets within a row (kk = 0/1)
    const int sw0 = ((lg ^ (lr & 7)) << 3);
    const int sw1 = (((4 | lg) ^ (lr & 7)) << 3);

    const int kt0 = sp * 32;

    // prologue: tile 0 -> LDS[0]; issue tile 1 loads
    {
        uint4 k0a = *(const uint4*)(Kbase + (size_t)kt0 * 8192);
        uint4 k0b = *(const uint4*)(Kbase + (size_t)kt0 * 8192 + 16);
        uint4 v0a = *(const uint4*)(Vbase + kt0 * 128);
        uint4 v0b = *(const uint4*)(Vbase + kt0 * 128 + 16);
        *(uint4*)&Ks[0][se0] = k0a;  *(uint4*)&Ks[0][se1] = k0b;
        *(uint4*)&Vs[0][se0] = v0a;  *(uint4*)&Vs[0][se1] = v0b;
    }
    uint4 ka = *(const uint4*)(Kbase + (size_t)(kt0 + 1) * 8192);
    uint4 kb = *(const uint4*)(Kbase + (size_t)(kt0 + 1) * 8192 + 16);
    uint4 va = *(const uint4*)(Vbase + (kt0 + 1) * 128);
    uint4 vb = *(const uint4*)(Vbase + (kt0 + 1) * 128 + 16);
    __syncthreads();

    f32x4 zz = {0.f, 0.f, 0.f, 0.f};
    f32x4 o[4];
    float m[4], l[4];
    #pragma unroll
    for (int r = 0; r < 4; r++) { m[r] = -INFINITY; l[r] = 0.f; o[r] = zz; }

    for (int t = 0; t < 32; ++t) {
        const u16* ks = Ks[t & 1];
        const u16* vs = Vs[t & 1];

        // ---- QK^T ----
        f32x4 s[4];
        #pragma unroll
        for (int ct = 0; ct < 4; ct++) {
            bf16x8 b0 = *(const bf16x8*)&ks[(ct * 16 + lr) * 64 + sw0];
            bf16x8 b1 = *(const bf16x8*)&ks[(ct * 16 + lr) * 64 + sw1];
            f32x4 acc = __builtin_amdgcn_mfma_f32_16x16x32_bf16(aq0, b0, zz, 0, 0, 0);
            acc = __builtin_amdgcn_mfma_f32_16x16x32_bf16(aq1, b1, acc, 0, 0, 0);
            s[ct] = acc;
        }

        // ---- online softmax (exp2 domain) ----
        float pv[4][4];
        #pragma unroll
        for (int r = 0; r < 4; r++) {
            float mx = fmaxf(fmaxf(s[0][r], s[1][r]), fmaxf(s[2][r], s[3][r]));
            #pragma unroll
            for (int off = 1; off < 16; off <<= 1) mx = fmaxf(mx, __shfl_xor(mx, off));
            float mnew = fmaxf(m[r], mx);
            float alpha = exp2f(m[r] - mnew);
            m[r] = mnew;
            float ps = 0.f;
            #pragma unroll
            for (int ct = 0; ct < 4; ct++) {
                float p = exp2f(s[ct][r] - mnew);
                pv[ct][r] = p;
                ps += p;
            }
            #pragma unroll
            for (int off = 1; off < 16; off <<= 1) ps += __shfl_xor(ps, off);
            l[r] = l[r] * alpha + ps;
            #pragma unroll
            for (int ct = 0; ct < 4; ct++) o[ct][r] *= alpha;
        }

        // ---- P -> LDS (swizzled) ----
        #pragma unroll
        for (int r = 0; r < 4; r++) {
            int q = lg * 4 + r;
            #pragma unroll
            for (int ct = 0; ct < 4; ct++) {
                int key = ct * 16 + lr;
                Ps[w][q * 64 + (key ^ ((q & 7) << 3))] = f2bf(pv[ct][r]);
            }
        }
        asm volatile("s_waitcnt lgkmcnt(0)" ::: "memory");

        // ---- PV ----
        #pragma unroll
        for (int kk = 0; kk < 2; kk++) {
            const int sw = kk ? sw1 : sw0;
            bf16x8 pa = *(const bf16x8*)&Ps[w][lr * 64 + sw];
            #pragma unroll
            for (int ct = 0; ct < 4; ct++) {
                bf16x8 bv = *(const bf16x8*)&vs[(ct * 16 + lr) * 64 + sw];
                o[ct] = __builtin_amdgcn_mfma_f32_16x16x32_bf16(pa, bv, o[ct], 0, 0, 0);
            }
        }

        // ---- write next tile from regs, barrier, issue loads for t+2 ----
        if (t < 31) {
            u16* kd = Ks[(t + 1) & 1];
            u16* vd = Vs[(t + 1) & 1];
            *(uint4*)&kd[se0] = ka;  *(uint4*)&kd[se1] = kb;
            *(uint4*)&vd[se0] = va;  *(uint4*)&vd[se1] = vb;
        }
        __syncthreads();
        if (t < 30) {
            int kt = kt0 + t + 2;
            ka = *(const uint4*)(Kbase + (size_t)kt * 8192);
            kb = *(const uint4*)(Kbase + (size_t)kt * 8192 + 16);
            va = *(const uint4*)(Vbase + kt * 128);
            vb = *(const uint4*)(Vbase + kt * 128 + 16);
        }
    }

    // ---- epilogue: normalized partial O (bf16) + (m,l) ----
    float inv[4];
    #pragma unroll
    for (int r = 0; r < 4; r++) inv[r] = 1.f / l[r];
    u16* op = Opart + (size_t)sp * ((size_t)B_ * N_ * C_)
            + ((size_t)(b * N_ + qt * 64 + w * 16)) * C_;
    #pragma unroll
    for (int r = 0; r < 4; r++)
        #pragma unroll
        for (int ct = 0; ct < 4; ct++)
            op[(lg * 4 + r) * C_ + ct * 16 + lr] = f2bf(o[ct][r] * inv[r]);
    if (lr == 0) {
        float* mlp = ml + ((size_t)sp * (B_ * N_) + b * N_ + qt * 64 + w * 16 + lg * 4) * 2;
        #pragma unroll
        for (int r = 0; r < 4; r++) { mlp[r * 2] = m[r]; mlp[r * 2 + 1] = l[r]; }
    }
}

// ---------------- Kernel 5: combine KV-split partials ----------------
__global__ __launch_bounds__(256) void combine_kernel(
    const u16* __restrict__ Opart, const float* __restrict__ ml,
    u16* __restrict__ Og) {
    int p = blockIdx.x * 256 + threadIdx.x;  // pixel 0..16383
    float m0 = ml[(size_t)p * 2],           l0 = ml[(size_t)p * 2 + 1];
    float m1 = ml[(size_t)(16384 + p) * 2], l1 = ml[(size_t)(16384 + p) * 2 + 1];
    float M = fmaxf(m0, m1);
    float w0 = l0 * exp2f(m0 - M), w1 = l1 * exp2f(m1 - M);
    float d = 1.f / (w0 + w1);
    float a0 = w0 * d, a1 = w1 * d;
    const u16* o0 = Opart + (size_t)p * 64;
    const u16* o1 = Opart + (size_t)(16384 + p) * 64;
    u16* og = Og + (size_t)p * 64;
    #pragma unroll
    for (int c8 = 0; c8 < 8; c8++) {
        u16 x0[8], x1[8], y[8];
        *(uint4*)x0 = *(const uint4*)(o0 + c8 * 8);
        *(uint4*)x1 = *(const uint4*)(o1 + c8 * 8);
        #pragma unroll
        for (int j = 0; j < 8; j++) y[j] = f2bf(a0 * bf2f(x0[j]) + a1 * bf2f(x1[j]));
        *(uint4*)(og + c8 * 8) = *(uint4*)y;
    }
}

// ---------------- Kernel 6: output projection + residual ----------------
__global__ __launch_bounds__(256) void proj_kernel(
    const u16* __restrict__ Og, const float* __restrict__ Wp,
    const float* __restrict__ bp, const float* __restrict__ x,
    float* __restrict__ out) {
    __shared__ __align__(16) float ot[64][68];
    __shared__ __align__(16) float wpl[64][68];
    const int b = blockIdx.x >> 6;
    const int nt = blockIdx.x & 63;
    const int tid = threadIdx.x;

    #pragma unroll
    for (int k = 0; k < 4; k++) {
        int i = tid + k * 256;
        float4 v = ((const float4*)Wp)[i];
        *(float4*)&wpl[i >> 4][(i & 15) * 4] = v;
    }
    {
        const uint4* src = (const uint4*)(Og + ((size_t)(b * N_ + nt * 64)) * C_);
        #pragma unroll
        for (int k = 0; k < 2; k++) {
            int i = tid + k * 256;
            int p = i >> 3, c8 = i & 7;
            u16 tmp[8];
            *(uint4*)tmp = src[i];
            #pragma unroll
            for (int j = 0; j < 8; j++) ot[p][c8 * 8 + j] = bf2f(tmp[j]);
        }
    }
    __syncthreads();

    const int co = tid >> 2, ng = tid & 3;
    float acc[16];
    #pragma unroll
    for (int p = 0; p < 16; p++) acc[p] = 0.f;
    #pragma unroll
    for (int c4 = 0; c4 < 16; c4++) {
        float4 w4 = *(float4*)&wpl[co][c4 * 4];
        #pragma unroll
        for (int p = 0; p < 16; p++) {
            float4 o4 = *(float4*)&ot[ng + p * 4][c4 * 4];
            acc[p] += w4.x * o4.x + w4.y * o4.y + w4.z * o4.z + w4.w * o4.w;
        }
    }
    float bias = bp[co];
    const size_t base = (size_t)(b * C_ + co) * N_ + (size_t)nt * 64;
    #pragma unroll
    for (int p = 0; p < 16; p++) {
        int n = ng + p * 4;
        out[base + n] = x[base + n] + bias + acc[p];
    }
}

extern "C" void kernel_launch(void* const* d_in, const int* in_sizes, int n_in,
                              void* d_out, int out_size, void* d_ws, size_t ws_size,
                              hipStream_t stream) {
    const float* x     = (const float*)d_in[0];
    const float* gamma = (const float*)d_in[1];
    const float* beta  = (const float*)d_in[2];
    const float* Wq    = (const float*)d_in[3];
    const float* bq    = (const float*)d_in[4];
    const float* Wk    = (const float*)d_in[5];
    const float* bk    = (const float*)d_in[6];
    const float* Wv    = (const float*)d_in[7];
    const float* bv    = (const float*)d_in[8];
    const float* Wp    = (const float*)d_in[9];
    const float* bp    = (const float*)d_in[10];
    float* out = (float*)d_out;

    const size_t elems = (size_t)B_ * N_ * C_;  // 1M
    float* partials = (float*)d_ws;             // 4 KB region
    u16* xn = (u16*)((char*)d_ws + 4096);       // 2 MB; ml overlays it after qkv
    float* ml = (float*)xn;                     // 512 KB (xn is dead by then)
    u16* Qb = xn + elems;
    u16* Kb = Qb + elems;
    u16* Vt = Kb + elems;
    u16* Ob = Vt + elems;
    u16* Opart = (u16*)d_out;                   // 4 MB scratch; proj overwrites at end

    gn_reduce<<<256, 256, 0, stream>>>(x, partials);
    gn_apply<<<256, 256, 0, stream>>>(x, gamma, beta, partials, xn);
    qkv_kernel<<<256, 256, 0, stream>>>(xn, Wq, bq, Wk, bk, Wv, bv, Qb, Kb, Vt);
    flash_kernel<<<512, 256, 0, stream>>>(Qb, Kb, Vt, Opart, ml);
    combine_kernel<<<64, 256, 0, stream>>>(Opart, ml, Ob);
    proj_kernel<<<256, 256, 0, stream>>>(Ob, Wp, bp, x, out);
}

// Round 3
// 85.444 us; speedup vs baseline: 1.9704x; 1.4954x over previous
//
#include <hip/hip_runtime.h>
#include <math.h>

#define B_ 4
#define C_ 64
#define N_ 4096

typedef unsigned short u16;
typedef __attribute__((ext_vector_type(8))) short bf16x8;
typedef __attribute__((ext_vector_type(4))) float f32x4;

__device__ __forceinline__ u16 f2bf(float f) {
    unsigned u = __float_as_uint(f);
    u += 0x7fff + ((u >> 16) & 1);
    return (u16)(u >> 16);
}
__device__ __forceinline__ float bf2f(u16 h) {
    return __uint_as_float(((unsigned)h) << 16);
}

// DPP cross-lane (within 16-lane row): VALU-rate, no LDS latency.
template <int CTRL>
__device__ __forceinline__ float dppf(float x) {
    return __uint_as_float((unsigned)__builtin_amdgcn_mov_dpp(
        (int)__float_as_uint(x), CTRL, 0xF, 0xF, true));
}
__device__ __forceinline__ float rowmax16(float x) {
    x = fmaxf(x, dppf<0xB1>(x));   // quad_perm xor1
    x = fmaxf(x, dppf<0x4E>(x));   // quad_perm xor2
    x = fmaxf(x, dppf<0x124>(x));  // row_ror:4
    x = fmaxf(x, dppf<0x128>(x));  // row_ror:8
    return x;
}
__device__ __forceinline__ float rowsum16(float x) {
    x += dppf<0xB1>(x);
    x += dppf<0x4E>(x);
    x += dppf<0x124>(x);
    x += dppf<0x128>(x);
    return x;
}

// ---------------- Kernel 1: GroupNorm partial reduction ----------------
__global__ __launch_bounds__(256) void gn_reduce(const float* __restrict__ x,
                                                 float* __restrict__ partials) {
    int bg = blockIdx.x >> 3, chunk = blockIdx.x & 7;
    const float4* xv = (const float4*)(x + (size_t)bg * 32768 + (size_t)chunk * 4096);
    float s = 0.f, ss = 0.f;
    #pragma unroll
    for (int k = 0; k < 4; k++) {
        float4 v = xv[threadIdx.x + 256 * k];
        s += v.x + v.y + v.z + v.w;
        ss += v.x * v.x + v.y * v.y + v.z * v.z + v.w * v.w;
    }
    #pragma unroll
    for (int off = 1; off < 64; off <<= 1) {
        s += __shfl_xor(s, off);
        ss += __shfl_xor(ss, off);
    }
    __shared__ float red[2][4];
    int w = threadIdx.x >> 6;
    if ((threadIdx.x & 63) == 0) { red[0][w] = s; red[1][w] = ss; }
    __syncthreads();
    if (threadIdx.x == 0) {
        s = red[0][0] + red[0][1] + red[0][2] + red[0][3];
        ss = red[1][0] + red[1][1] + red[1][2] + red[1][3];
        partials[bg * 16 + chunk * 2] = s;
        partials[bg * 16 + chunk * 2 + 1] = ss;
    }
}

// ---------------- Kernel 2: GroupNorm apply -> xn bf16 [B, N, C] ----------------
__global__ __launch_bounds__(256) void gn_apply(const float* __restrict__ x,
                                                const float* __restrict__ gamma,
                                                const float* __restrict__ beta,
                                                const float* __restrict__ partials,
                                                u16* __restrict__ xn) {
    int bg = blockIdx.x >> 3, chunk = blockIdx.x & 7;
    int b = bg >> 3, g = bg & 7;
    float s = 0.f, ss = 0.f;
    #pragma unroll
    for (int i = 0; i < 8; i++) {
        s += partials[bg * 16 + i * 2];
        ss += partials[bg * 16 + i * 2 + 1];
    }
    float mean = s * (1.f / 32768.f);
    float var = ss * (1.f / 32768.f) - mean * mean;
    float rstd = rsqrtf(var + 1e-5f);
    float ga[8], bb[8];
    #pragma unroll
    for (int j = 0; j < 8; j++) {
        float gm = gamma[g * 8 + j] * rstd;
        ga[j] = gm;
        bb[j] = beta[g * 8 + j] - mean * gm;
    }
    const float* xp = x + (size_t)(b * C_ + g * 8) * N_;
    u16* outp = xn + (size_t)b * N_ * C_ + g * 8;
    int n0 = chunk * 512;
    for (int it = 0; it < 2; it++) {
        int n = n0 + threadIdx.x + it * 256;
        u16 pk[8];
        #pragma unroll
        for (int j = 0; j < 8; j++) {
            float v = xp[j * N_ + n];
            pk[j] = f2bf(v * ga[j] + bb[j]);
        }
        *(uint4*)(outp + (size_t)n * C_) = *(uint4*)pk;
    }
}

// ---------------- Kernel 3: QKV projections via MFMA ----------------
// Computes O^T = W * xn^T per 64-pixel tile. Q,K -> [B,N,C] bf16 (Q pre-scaled
// by 0.125*log2e); V -> [B,C,N] bf16. grid 256 = b*64 tiles, 256 threads.
__global__ __launch_bounds__(256) void qkv_kernel(
    const u16* __restrict__ xn,
    const float* __restrict__ Wq, const float* __restrict__ bq,
    const float* __restrict__ Wk, const float* __restrict__ bk,
    const float* __restrict__ Wv, const float* __restrict__ bv,
    u16* __restrict__ Qo, u16* __restrict__ Ko, u16* __restrict__ Vt) {
    __shared__ __align__(16) u16 wt[3][64][64];  // bf16 weights, XOR-swizzled rows
    __shared__ __align__(16) u16 xs[64][64];     // xn tile, XOR-swizzled rows
    __shared__ __align__(16) u16 odt[64][72];    // output staging (padded)

    const int b = blockIdx.x >> 6;
    const int nt = blockIdx.x & 63;
    const int tid = threadIdx.x;
    const float* Ws[3] = {Wq, Wk, Wv};
    const float* bs[3] = {bq, bk, bv};

    {   // stage weights: fp32 -> bf16, swizzled (block ^= row&7)
        const int rw = tid >> 2, qd = tid & 3;
        #pragma unroll
        for (int s = 0; s < 3; s++) {
            const float4* wsrc = (const float4*)(Ws[s] + rw * 64 + qd * 16);
            float4 f0 = wsrc[0], f1 = wsrc[1], f2 = wsrc[2], f3 = wsrc[3];
            u16 pk[16];
            pk[0]=f2bf(f0.x); pk[1]=f2bf(f0.y); pk[2]=f2bf(f0.z); pk[3]=f2bf(f0.w);
            pk[4]=f2bf(f1.x); pk[5]=f2bf(f1.y); pk[6]=f2bf(f1.z); pk[7]=f2bf(f1.w);
            pk[8]=f2bf(f2.x); pk[9]=f2bf(f2.y); pk[10]=f2bf(f2.z); pk[11]=f2bf(f2.w);
            pk[12]=f2bf(f3.x); pk[13]=f2bf(f3.y); pk[14]=f2bf(f3.z); pk[15]=f2bf(f3.w);
            int blk0 = (2 * qd) ^ (rw & 7), blk1 = (2 * qd + 1) ^ (rw & 7);
            *(uint4*)&wt[s][rw][blk0 * 8] = *(uint4*)&pk[0];
            *(uint4*)&wt[s][rw][blk1 * 8] = *(uint4*)&pk[8];
        }
    }
    {   // stage xn tile (swizzled)
        #pragma unroll
        for (int k2 = 0; k2 < 2; k2++) {
            int c = tid + k2 * 256;
            int px = c >> 3, blk = c & 7;
            uint4 v = *(const uint4*)(xn + ((size_t)(b * N_ + nt * 64 + px)) * 64 + blk * 8);
            *(uint4*)&xs[px][(blk ^ (px & 7)) * 8] = v;
        }
    }
    __syncthreads();

    const int lane = tid & 63, w = tid >> 6;
    const int lr = lane & 15, lg = lane >> 4;
    const f32x4 zz = {0.f, 0.f, 0.f, 0.f};
    const int sa0 = (lg ^ (lr & 7)) * 8, sa1 = ((4 | lg) ^ (lr & 7)) * 8;

    #pragma unroll
    for (int s = 0; s < 3; s++) {
        bf16x8 a0 = *(const bf16x8*)&wt[s][w * 16 + lr][sa0];
        bf16x8 a1 = *(const bf16x8*)&wt[s][w * 16 + lr][sa1];
        float bias[4];
        #pragma unroll
        for (int r = 0; r < 4; r++) bias[r] = bs[s][w * 16 + lg * 4 + r];
        #pragma unroll
        for (int pt = 0; pt < 4; pt++) {
            bf16x8 b0 = *(const bf16x8*)&xs[pt * 16 + lr][sa0];
            bf16x8 b1 = *(const bf16x8*)&xs[pt * 16 + lr][sa1];
            f32x4 acc = __builtin_amdgcn_mfma_f32_16x16x32_bf16(a0, b0, zz, 0, 0, 0);
            acc = __builtin_amdgcn_mfma_f32_16x16x32_bf16(a1, b1, acc, 0, 0, 0);
            if (s == 0) {
                #pragma unroll
                for (int r = 0; r < 4; r++)
                    odt[pt * 16 + lr][w * 16 + lg * 4 + r] = f2bf((acc[r] + bias[r]) * 0.18033688f);
            } else if (s == 1) {
                #pragma unroll
                for (int r = 0; r < 4; r++)
                    odt[pt * 16 + lr][w * 16 + lg * 4 + r] = f2bf(acc[r] + bias[r]);
            } else {
                #pragma unroll
                for (int r = 0; r < 4; r++)
                    odt[w * 16 + lg * 4 + r][pt * 16 + lr] = f2bf(acc[r] + bias[r]);
            }
        }
        __syncthreads();  // odt complete
        if (s < 2) {
            u16* dst = (s == 0 ? Qo : Ko) + ((size_t)(b * N_ + nt * 64)) * 64;
            #pragma unroll
            for (int k2 = 0; k2 < 2; k2++) {
                int c = tid + k2 * 256;
                int px = c >> 3, blk = c & 7;
                *(uint4*)(dst + (size_t)px * 64 + blk * 8) = *(const uint4*)&odt[px][blk * 8];
            }
        } else {
            #pragma unroll
            for (int k2 = 0; k2 < 2; k2++) {
                int c = tid + k2 * 256;
                int co = c >> 3, blk = c & 7;
                *(uint4*)(Vt + ((size_t)(b * 64 + co)) * N_ + nt * 64 + blk * 8) =
                    *(const uint4*)&odt[co][blk * 8];
            }
        }
        __syncthreads();  // odt consumed before next set overwrites
    }
}

// ---------------- Kernel 4: flash attention, KV-split x2, pipelined, swizzled ----------------
__global__ __launch_bounds__(256) void flash_kernel(
    const u16* __restrict__ Qg, const u16* __restrict__ Kg,
    const u16* __restrict__ Vg, u16* __restrict__ Opart, float* __restrict__ ml) {
    __shared__ __align__(16) u16 Ks[2][4096];
    __shared__ __align__(16) u16 Vs[2][4096];
    __shared__ __align__(16) u16 Ps[4][1024];

    const int sp = blockIdx.x & 1;
    const int qt = (blockIdx.x >> 1) & 63;
    const int b  = blockIdx.x >> 7;
    const int tid = threadIdx.x;
    const int w = tid >> 6, lane = tid & 63;
    const int lr = lane & 15, lg = lane >> 4;

    const u16* qrow = Qg + ((size_t)(b * N_ + qt * 64 + w * 16 + lr)) * C_;
    bf16x8 aq0 = *(const bf16x8*)(qrow + lg * 8);
    bf16x8 aq1 = *(const bf16x8*)(qrow + 32 + lg * 8);

    const int srow = tid >> 2;
    const int scb  = (tid & 3) * 32;
    const char* Kbase = (const char*)(Kg + (size_t)b * N_ * C_) + (size_t)srow * 128 + scb;
    const char* Vbase = (const char*)(Vg + (size_t)b * C_ * N_) + (size_t)srow * (N_ * 2) + scb;
    const int se0 = srow * 64 + (((scb)      ^ ((srow & 7) << 4)) >> 1);
    const int se1 = srow * 64 + (((scb + 16) ^ ((srow & 7) << 4)) >> 1);

    const int sw0 = ((lg ^ (lr & 7)) << 3);
    const int sw1 = (((4 | lg) ^ (lr & 7)) << 3);

    const int kt0 = sp * 32;

    {
        uint4 k0a = *(const uint4*)(Kbase + (size_t)kt0 * 8192);
        uint4 k0b = *(const uint4*)(Kbase + (size_t)kt0 * 8192 + 16);
        uint4 v0a = *(const uint4*)(Vbase + kt0 * 128);
        uint4 v0b = *(const uint4*)(Vbase + kt0 * 128 + 16);
        *(uint4*)&Ks[0][se0] = k0a;  *(uint4*)&Ks[0][se1] = k0b;
        *(uint4*)&Vs[0][se0] = v0a;  *(uint4*)&Vs[0][se1] = v0b;
    }
    uint4 ka = *(const uint4*)(Kbase + (size_t)(kt0 + 1) * 8192);
    uint4 kb = *(const uint4*)(Kbase + (size_t)(kt0 + 1) * 8192 + 16);
    uint4 va = *(const uint4*)(Vbase + (kt0 + 1) * 128);
    uint4 vb = *(const uint4*)(Vbase + (kt0 + 1) * 128 + 16);
    __syncthreads();

    f32x4 zz = {0.f, 0.f, 0.f, 0.f};
    f32x4 o[4];
    float m[4], l[4];
    #pragma unroll
    for (int r = 0; r < 4; r++) { m[r] = -INFINITY; l[r] = 0.f; o[r] = zz; }

    for (int t = 0; t < 32; ++t) {
        const u16* ks = Ks[t & 1];
        const u16* vs = Vs[t & 1];

        // ---- QK^T ----
        f32x4 s[4];
        __builtin_amdgcn_s_setprio(1);
        #pragma unroll
        for (int ct = 0; ct < 4; ct++) {
            bf16x8 b0 = *(const bf16x8*)&ks[(ct * 16 + lr) * 64 + sw0];
            bf16x8 b1 = *(const bf16x8*)&ks[(ct * 16 + lr) * 64 + sw1];
            f32x4 acc = __builtin_amdgcn_mfma_f32_16x16x32_bf16(aq0, b0, zz, 0, 0, 0);
            acc = __builtin_amdgcn_mfma_f32_16x16x32_bf16(aq1, b1, acc, 0, 0, 0);
            s[ct] = acc;
        }
        __builtin_amdgcn_s_setprio(0);

        // ---- online softmax (exp2 domain, DPP reductions, defer-max) ----
        float mx[4];
        #pragma unroll
        for (int r = 0; r < 4; r++) {
            float v = fmaxf(fmaxf(s[0][r], s[1][r]), fmaxf(s[2][r], s[3][r]));
            mx[r] = rowmax16(v);
        }
        float g = fmaxf(fmaxf(mx[0] - m[0], mx[1] - m[1]),
                        fmaxf(mx[2] - m[2], mx[3] - m[3]));
        if (!__all(g <= 8.f)) {
            #pragma unroll
            for (int r = 0; r < 4; r++) {
                float mnew = fmaxf(m[r], mx[r]);
                float alpha = exp2f(m[r] - mnew);
                m[r] = mnew;
                l[r] *= alpha;
                #pragma unroll
                for (int ct = 0; ct < 4; ct++) o[ct][r] *= alpha;
            }
        }
        float pv[4][4];
        #pragma unroll
        for (int r = 0; r < 4; r++) {
            float p0 = exp2f(s[0][r] - m[r]), p1 = exp2f(s[1][r] - m[r]);
            float p2 = exp2f(s[2][r] - m[r]), p3 = exp2f(s[3][r] - m[r]);
            pv[0][r] = p0; pv[1][r] = p1; pv[2][r] = p2; pv[3][r] = p3;
            l[r] += rowsum16((p0 + p1) + (p2 + p3));
        }

        // ---- P -> LDS (swizzled) ----
        #pragma unroll
        for (int r = 0; r < 4; r++) {
            int q = lg * 4 + r;
            #pragma unroll
            for (int ct = 0; ct < 4; ct++) {
                int key = ct * 16 + lr;
                Ps[w][q * 64 + (key ^ ((q & 7) << 3))] = f2bf(pv[ct][r]);
            }
        }
        asm volatile("s_waitcnt lgkmcnt(0)" ::: "memory");

        // ---- PV ----
        __builtin_amdgcn_s_setprio(1);
        #pragma unroll
        for (int kk = 0; kk < 2; kk++) {
            const int sw = kk ? sw1 : sw0;
            bf16x8 pa = *(const bf16x8*)&Ps[w][lr * 64 + sw];
            #pragma unroll
            for (int ct = 0; ct < 4; ct++) {
                bf16x8 bv = *(const bf16x8*)&vs[(ct * 16 + lr) * 64 + sw];
                o[ct] = __builtin_amdgcn_mfma_f32_16x16x32_bf16(pa, bv, o[ct], 0, 0, 0);
            }
        }
        __builtin_amdgcn_s_setprio(0);

        // ---- write next tile from regs, barrier, issue loads for t+2 ----
        if (t < 31) {
            u16* kd = Ks[(t + 1) & 1];
            u16* vd = Vs[(t + 1) & 1];
            *(uint4*)&kd[se0] = ka;  *(uint4*)&kd[se1] = kb;
            *(uint4*)&vd[se0] = va;  *(uint4*)&vd[se1] = vb;
        }
        __syncthreads();
        if (t < 30) {
            int kt = kt0 + t + 2;
            ka = *(const uint4*)(Kbase + (size_t)kt * 8192);
            kb = *(const uint4*)(Kbase + (size_t)kt * 8192 + 16);
            va = *(const uint4*)(Vbase + kt * 128);
            vb = *(const uint4*)(Vbase + kt * 128 + 16);
        }
    }

    // ---- epilogue: normalized partial O (bf16) + (m,l) ----
    float inv[4];
    #pragma unroll
    for (int r = 0; r < 4; r++) inv[r] = 1.f / l[r];
    u16* op = Opart + (size_t)sp * ((size_t)B_ * N_ * C_)
            + ((size_t)(b * N_ + qt * 64 + w * 16)) * C_;
    #pragma unroll
    for (int r = 0; r < 4; r++)
        #pragma unroll
        for (int ct = 0; ct < 4; ct++)
            op[(lg * 4 + r) * C_ + ct * 16 + lr] = f2bf(o[ct][r] * inv[r]);
    if (lr == 0) {
        float* mlp = ml + ((size_t)sp * (B_ * N_) + b * N_ + qt * 64 + w * 16 + lg * 4) * 2;
        #pragma unroll
        for (int r = 0; r < 4; r++) { mlp[r * 2] = m[r]; mlp[r * 2 + 1] = l[r]; }
    }
}

// ---------------- Kernel 5: combine KV-split partials ----------------
__global__ __launch_bounds__(256) void combine_kernel(
    const u16* __restrict__ Opart, const float* __restrict__ ml,
    u16* __restrict__ Og) {
    int p = blockIdx.x * 256 + threadIdx.x;
    float m0 = ml[(size_t)p * 2],           l0 = ml[(size_t)p * 2 + 1];
    float m1 = ml[(size_t)(16384 + p) * 2], l1 = ml[(size_t)(16384 + p) * 2 + 1];
    float M = fmaxf(m0, m1);
    float w0 = l0 * exp2f(m0 - M), w1 = l1 * exp2f(m1 - M);
    float d = 1.f / (w0 + w1);
    float a0 = w0 * d, a1 = w1 * d;
    const u16* o0 = Opart + (size_t)p * 64;
    const u16* o1 = Opart + (size_t)(16384 + p) * 64;
    u16* og = Og + (size_t)p * 64;
    #pragma unroll
    for (int c8 = 0; c8 < 8; c8++) {
        u16 x0[8], x1[8], y[8];
        *(uint4*)x0 = *(const uint4*)(o0 + c8 * 8);
        *(uint4*)x1 = *(const uint4*)(o1 + c8 * 8);
        #pragma unroll
        for (int j = 0; j < 8; j++) y[j] = f2bf(a0 * bf2f(x0[j]) + a1 * bf2f(x1[j]));
        *(uint4*)(og + c8 * 8) = *(uint4*)y;
    }
}

// ---------------- Kernel 6: output projection + residual via MFMA ----------------
__global__ __launch_bounds__(256) void proj_kernel(
    const u16* __restrict__ Og, const float* __restrict__ Wp,
    const float* __restrict__ bp, const float* __restrict__ x,
    float* __restrict__ out) {
    __shared__ __align__(16) u16 wp[64][64];
    __shared__ __align__(16) u16 og[64][64];
    const int b = blockIdx.x >> 6;
    const int nt = blockIdx.x & 63;
    const int tid = threadIdx.x;

    {   // stage Wp bf16 swizzled
        const int rw = tid >> 2, qd = tid & 3;
        const float4* wsrc = (const float4*)(Wp + rw * 64 + qd * 16);
        float4 f0 = wsrc[0], f1 = wsrc[1], f2 = wsrc[2], f3 = wsrc[3];
        u16 pk[16];
        pk[0]=f2bf(f0.x); pk[1]=f2bf(f0.y); pk[2]=f2bf(f0.z); pk[3]=f2bf(f0.w);
        pk[4]=f2bf(f1.x); pk[5]=f2bf(f1.y); pk[6]=f2bf(f1.z); pk[7]=f2bf(f1.w);
        pk[8]=f2bf(f2.x); pk[9]=f2bf(f2.y); pk[10]=f2bf(f2.z); pk[11]=f2bf(f2.w);
        pk[12]=f2bf(f3.x); pk[13]=f2bf(f3.y); pk[14]=f2bf(f3.z); pk[15]=f2bf(f3.w);
        int blk0 = (2 * qd) ^ (rw & 7), blk1 = (2 * qd + 1) ^ (rw & 7);
        *(uint4*)&wp[rw][blk0 * 8] = *(uint4*)&pk[0];
        *(uint4*)&wp[rw][blk1 * 8] = *(uint4*)&pk[8];
    }
    {
        #pragma unroll
        for (int k2 = 0; k2 < 2; k2++) {
            int c = tid + k2 * 256;
            int px = c >> 3, blk = c & 7;
            uint4 v = *(const uint4*)(Og + ((size_t)(b * N_ + nt * 64 + px)) * 64 + blk * 8);
            *(uint4*)&og[px][(blk ^ (px & 7)) * 8] = v;
        }
    }
    __syncthreads();

    const int lane = tid & 63, w = tid >> 6;
    const int lr = lane & 15, lg = lane >> 4;
    const f32x4 zz = {0.f, 0.f, 0.f, 0.f};
    const int sa0 = (lg ^ (lr & 7)) * 8, sa1 = ((4 | lg) ^ (lr & 7)) * 8;

    bf16x8 a0 = *(const bf16x8*)&wp[w * 16 + lr][sa0];
    bf16x8 a1 = *(const bf16x8*)&wp[w * 16 + lr][sa1];
    float bias[4];
    #pragma unroll
    for (int r = 0; r < 4; r++) bias[r] = bp[w * 16 + lg * 4 + r];

    #pragma unroll
    for (int pt = 0; pt < 4; pt++) {
        bf16x8 b0 = *(const bf16x8*)&og[pt * 16 + lr][sa0];
        bf16x8 b1 = *(const bf16x8*)&og[pt * 16 + lr][sa1];
        f32x4 acc = __builtin_amdgcn_mfma_f32_16x16x32_bf16(a0, b0, zz, 0, 0, 0);
        acc = __builtin_amdgcn_mfma_f32_16x16x32_bf16(a1, b1, acc, 0, 0, 0);
        #pragma unroll
        for (int r = 0; r < 4; r++) {
            int cout = w * 16 + lg * 4 + r;
            int px = pt * 16 + lr;
            size_t idx = ((size_t)(b * 64 + cout)) * N_ + nt * 64 + px;
            out[idx] = x[idx] + bias[r] + acc[r];
        }
    }
}

extern "C" void kernel_launch(void* const* d_in, const int* in_sizes, int n_in,
                              void* d_out, int out_size, void* d_ws, size_t ws_size,
                              hipStream_t stream) {
    const float* x     = (const float*)d_in[0];
    const float* gamma = (const float*)d_in[1];
    const float* beta  = (const float*)d_in[2];
    const float* Wq    = (const float*)d_in[3];
    const float* bq    = (const float*)d_in[4];
    const float* Wk    = (const float*)d_in[5];
    const float* bk    = (const float*)d_in[6];
    const float* Wv    = (const float*)d_in[7];
    const float* bv    = (const float*)d_in[8];
    const float* Wp    = (const float*)d_in[9];
    const float* bp    = (const float*)d_in[10];
    float* out = (float*)d_out;

    const size_t elems = (size_t)B_ * N_ * C_;  // 1M
    float* partials = (float*)d_ws;             // 4 KB region
    u16* xn = (u16*)((char*)d_ws + 4096);       // 2 MB; ml overlays it after qkv
    float* ml = (float*)xn;                     // (xn is dead by then)
    u16* Qb = xn + elems;
    u16* Kb = Qb + elems;
    u16* Vt = Kb + elems;
    u16* Ob = Vt + elems;
    u16* Opart = (u16*)d_out;                   // 4 MB scratch; proj overwrites at end

    gn_reduce<<<256, 256, 0, stream>>>(x, partials);
    gn_apply<<<256, 256, 0, stream>>>(x, gamma, beta, partials, xn);
    qkv_kernel<<<256, 256, 0, stream>>>(xn, Wq, bq, Wk, bk, Wv, bv, Qb, Kb, Vt);
    flash_kernel<<<512, 256, 0, stream>>>(Qb, Kb, Vt, Opart, ml);
    combine_kernel<<<64, 256, 0, stream>>>(Opart, ml, Ob);
    proj_kernel<<<256, 256, 0, stream>>>(Ob, Wp, bp, x, out);
}

// Round 4
// 63.534 us; speedup vs baseline: 2.6499x; 1.3449x over previous
//
#include <hip/hip_runtime.h>
#include <math.h>

#define B_ 4
#define C_ 64
#define N_ 4096

typedef unsigned short u16;
typedef __attribute__((ext_vector_type(8))) short bf16x8;
typedef __attribute__((ext_vector_type(4))) float f32x4;

__device__ __forceinline__ u16 f2bf(float f) {
    unsigned u = __float_as_uint(f);
    u += 0x7fff + ((u >> 16) & 1);
    return (u16)(u >> 16);
}
__device__ __forceinline__ float bf2f(u16 h) {
    return __uint_as_float(((unsigned)h) << 16);
}

// ---------------- Kernel 1: GroupNorm partial reduction ----------------
__global__ __launch_bounds__(256) void gn_reduce(const float* __restrict__ x,
                                                 float* __restrict__ partials) {
    int bg = blockIdx.x >> 3, chunk = blockIdx.x & 7;
    const float4* xv = (const float4*)(x + (size_t)bg * 32768 + (size_t)chunk * 4096);
    float s = 0.f, ss = 0.f;
    #pragma unroll
    for (int k = 0; k < 4; k++) {
        float4 v = xv[threadIdx.x + 256 * k];
        s += v.x + v.y + v.z + v.w;
        ss += v.x * v.x + v.y * v.y + v.z * v.z + v.w * v.w;
    }
    #pragma unroll
    for (int off = 1; off < 64; off <<= 1) {
        s += __shfl_xor(s, off);
        ss += __shfl_xor(ss, off);
    }
    __shared__ float red[2][4];
    int w = threadIdx.x >> 6;
    if ((threadIdx.x & 63) == 0) { red[0][w] = s; red[1][w] = ss; }
    __syncthreads();
    if (threadIdx.x == 0) {
        s = red[0][0] + red[0][1] + red[0][2] + red[0][3];
        ss = red[1][0] + red[1][1] + red[1][2] + red[1][3];
        partials[bg * 16 + chunk * 2] = s;
        partials[bg * 16 + chunk * 2 + 1] = ss;
    }
}

// ---------------- Kernel 2: fused GroupNorm-apply + QKV projections (MFMA) ----------------
// Reads x [B,C,N] fp32 + GN partials; computes xn inline; Q,K -> [B,N,C] bf16
// (Q pre-scaled by 0.125*log2e), V -> [B,C,N] bf16.
__global__ __launch_bounds__(256) void qkv_kernel(
    const float* __restrict__ x, const float* __restrict__ gamma,
    const float* __restrict__ beta, const float* __restrict__ partials,
    const float* __restrict__ Wq, const float* __restrict__ bq,
    const float* __restrict__ Wk, const float* __restrict__ bk,
    const float* __restrict__ Wv, const float* __restrict__ bv,
    u16* __restrict__ Qo, u16* __restrict__ Ko, u16* __restrict__ Vt) {
    __shared__ __align__(16) u16 wt[3][64][64];  // bf16 weights, XOR-swizzled rows
    __shared__ __align__(16) u16 xs[64][64];     // xn tile [px][ch], swizzled
    __shared__ __align__(16) u16 odt[64][72];    // output staging (padded)

    const int b = blockIdx.x >> 6;
    const int nt = blockIdx.x & 63;
    const int tid = threadIdx.x;
    const float* Ws[3] = {Wq, Wk, Wv};
    const float* bs[3] = {bq, bk, bv};

    {   // stage weights: fp32 -> bf16, swizzled (block ^= row&7)
        const int rw = tid >> 2, qd = tid & 3;
        #pragma unroll
        for (int s = 0; s < 3; s++) {
            const float4* wsrc = (const float4*)(Ws[s] + rw * 64 + qd * 16);
            float4 f0 = wsrc[0], f1 = wsrc[1], f2 = wsrc[2], f3 = wsrc[3];
            u16 pk[16];
            pk[0]=f2bf(f0.x); pk[1]=f2bf(f0.y); pk[2]=f2bf(f0.z); pk[3]=f2bf(f0.w);
            pk[4]=f2bf(f1.x); pk[5]=f2bf(f1.y); pk[6]=f2bf(f1.z); pk[7]=f2bf(f1.w);
            pk[8]=f2bf(f2.x); pk[9]=f2bf(f2.y); pk[10]=f2bf(f2.z); pk[11]=f2bf(f2.w);
            pk[12]=f2bf(f3.x); pk[13]=f2bf(f3.y); pk[14]=f2bf(f3.z); pk[15]=f2bf(f3.w);
            int blk0 = (2 * qd) ^ (rw & 7), blk1 = (2 * qd + 1) ^ (rw & 7);
            *(uint4*)&wt[s][rw][blk0 * 8] = *(uint4*)&pk[0];
            *(uint4*)&wt[s][rw][blk1 * 8] = *(uint4*)&pk[8];
        }
    }
    {   // GN-apply + stage xn tile: thread = (channel c, 16-pixel chunk)
        const int c = tid >> 2, px0 = (tid & 3) * 16;
        const int g = c >> 3, bg = b * 8 + g;
        float s = 0.f, ss = 0.f;
        #pragma unroll
        for (int i = 0; i < 8; i++) {
            s += partials[bg * 16 + i * 2];
            ss += partials[bg * 16 + i * 2 + 1];
        }
        float mean = s * (1.f / 32768.f);
        float var = ss * (1.f / 32768.f) - mean * mean;
        float rstd = rsqrtf(var + 1e-5f);
        float ga = gamma[c] * rstd;
        float bb = beta[c] - mean * ga;
        const float4* xp = (const float4*)(x + ((size_t)(b * 64 + c)) * N_ + nt * 64 + px0);
        float4 q0 = xp[0], q1 = xp[1], q2 = xp[2], q3 = xp[3];
        float vals[16] = {q0.x,q0.y,q0.z,q0.w, q1.x,q1.y,q1.z,q1.w,
                          q2.x,q2.y,q2.z,q2.w, q3.x,q3.y,q3.z,q3.w};
        #pragma unroll
        for (int e = 0; e < 16; e++) {
            int px = px0 + e;
            xs[px][((c >> 3) ^ (px & 7)) * 8 + (c & 7)] = f2bf(vals[e] * ga + bb);
        }
    }
    __syncthreads();

    const int lane = tid & 63, w = tid >> 6;
    const int lr = lane & 15, lg = lane >> 4;
    const f32x4 zz = {0.f, 0.f, 0.f, 0.f};
    const int sa0 = (lg ^ (lr & 7)) * 8, sa1 = ((4 | lg) ^ (lr & 7)) * 8;

    #pragma unroll
    for (int s = 0; s < 3; s++) {
        bf16x8 a0 = *(const bf16x8*)&wt[s][w * 16 + lr][sa0];
        bf16x8 a1 = *(const bf16x8*)&wt[s][w * 16 + lr][sa1];
        float bias[4];
        #pragma unroll
        for (int r = 0; r < 4; r++) bias[r] = bs[s][w * 16 + lg * 4 + r];
        #pragma unroll
        for (int pt = 0; pt < 4; pt++) {
            bf16x8 b0 = *(const bf16x8*)&xs[pt * 16 + lr][sa0];
            bf16x8 b1 = *(const bf16x8*)&xs[pt * 16 + lr][sa1];
            f32x4 acc = __builtin_amdgcn_mfma_f32_16x16x32_bf16(a0, b0, zz, 0, 0, 0);
            acc = __builtin_amdgcn_mfma_f32_16x16x32_bf16(a1, b1, acc, 0, 0, 0);
            if (s == 0) {
                #pragma unroll
                for (int r = 0; r < 4; r++)
                    odt[pt * 16 + lr][w * 16 + lg * 4 + r] = f2bf((acc[r] + bias[r]) * 0.18033688f);
            } else if (s == 1) {
                #pragma unroll
                for (int r = 0; r < 4; r++)
                    odt[pt * 16 + lr][w * 16 + lg * 4 + r] = f2bf(acc[r] + bias[r]);
            } else {
                #pragma unroll
                for (int r = 0; r < 4; r++)
                    odt[w * 16 + lg * 4 + r][pt * 16 + lr] = f2bf(acc[r] + bias[r]);
            }
        }
        __syncthreads();
        if (s < 2) {
            u16* dst = (s == 0 ? Qo : Ko) + ((size_t)(b * N_ + nt * 64)) * 64;
            #pragma unroll
            for (int k2 = 0; k2 < 2; k2++) {
                int c = tid + k2 * 256;
                int px = c >> 3, blk = c & 7;
                *(uint4*)(dst + (size_t)px * 64 + blk * 8) = *(const uint4*)&odt[px][blk * 8];
            }
        } else {
            #pragma unroll
            for (int k2 = 0; k2 < 2; k2++) {
                int c = tid + k2 * 256;
                int co = c >> 3, blk = c & 7;
                *(uint4*)(Vt + ((size_t)(b * 64 + co)) * N_ + nt * 64 + blk * 8) =
                    *(const uint4*)&odt[co][blk * 8];
            }
        }
        __syncthreads();
    }
}

// ---------------- Kernel 3: flash attention, fixed-max softmax ----------------
// grid 512 = B * 64 qtiles * 2 KV-splits. Fixed M=12 (exp2 domain) -> no online
// rescale; row-sum l computed by MFMA via a constant ones-row appended to V.
__global__ __launch_bounds__(256) void flash_kernel(
    const u16* __restrict__ Qg, const u16* __restrict__ Kg,
    const u16* __restrict__ Vg, u16* __restrict__ Opart, float* __restrict__ ml) {
    __shared__ __align__(16) u16 Ks[2][4096];
    __shared__ __align__(16) u16 Vs[2][5120];   // rows 0..63 = V^T; 64 = ones; 65..79 = 0
    __shared__ __align__(16) u16 Ps[4][1024];

    const int sp = blockIdx.x & 1;
    const int qt = (blockIdx.x >> 1) & 63;
    const int b  = blockIdx.x >> 7;
    const int tid = threadIdx.x;
    const int w = tid >> 6, lane = tid & 63;
    const int lr = lane & 15, lg = lane >> 4;

    // constant ones/zeros rows for both buffers (swizzle-invariant: constant per row)
    #pragma unroll
    for (int i = tid; i < 2048; i += 256) {
        int bufi = i >> 10, off = i & 1023;
        Vs[bufi][4096 + off] = (off < 64) ? (u16)0x3F80 : (u16)0;
    }

    const u16* qrow = Qg + ((size_t)(b * N_ + qt * 64 + w * 16 + lr)) * C_;
    bf16x8 aq0 = *(const bf16x8*)(qrow + lg * 8);
    bf16x8 aq1 = *(const bf16x8*)(qrow + 32 + lg * 8);

    const int srow = tid >> 2;
    const int scb  = (tid & 3) * 32;
    const char* Kbase = (const char*)(Kg + (size_t)b * N_ * C_) + (size_t)srow * 128 + scb;
    const char* Vbase = (const char*)(Vg + (size_t)b * C_ * N_) + (size_t)srow * (N_ * 2) + scb;
    const int se0 = srow * 64 + (((scb)      ^ ((srow & 7) << 4)) >> 1);
    const int se1 = srow * 64 + (((scb + 16) ^ ((srow & 7) << 4)) >> 1);

    const int sw0 = ((lg ^ (lr & 7)) << 3);
    const int sw1 = (((4 | lg) ^ (lr & 7)) << 3);

    const int kt0 = sp * 32;

    {
        uint4 k0a = *(const uint4*)(Kbase + (size_t)kt0 * 8192);
        uint4 k0b = *(const uint4*)(Kbase + (size_t)kt0 * 8192 + 16);
        uint4 v0a = *(const uint4*)(Vbase + kt0 * 128);
        uint4 v0b = *(const uint4*)(Vbase + kt0 * 128 + 16);
        *(uint4*)&Ks[0][se0] = k0a;  *(uint4*)&Ks[0][se1] = k0b;
        *(uint4*)&Vs[0][se0] = v0a;  *(uint4*)&Vs[0][se1] = v0b;
    }
    uint4 ka = *(const uint4*)(Kbase + (size_t)(kt0 + 1) * 8192);
    uint4 kb = *(const uint4*)(Kbase + (size_t)(kt0 + 1) * 8192 + 16);
    uint4 va = *(const uint4*)(Vbase + (kt0 + 1) * 128);
    uint4 vb = *(const uint4*)(Vbase + (kt0 + 1) * 128 + 16);
    __syncthreads();

    f32x4 zz = {0.f, 0.f, 0.f, 0.f};
    f32x4 o[5];
    #pragma unroll
    for (int ct = 0; ct < 5; ct++) o[ct] = zz;

    for (int t = 0; t < 32; ++t) {
        const u16* ks = Ks[t & 1];
        const u16* vs = Vs[t & 1];

        // ---- QK^T ----
        f32x4 s[4];
        __builtin_amdgcn_s_setprio(1);
        #pragma unroll
        for (int ct = 0; ct < 4; ct++) {
            bf16x8 b0 = *(const bf16x8*)&ks[(ct * 16 + lr) * 64 + sw0];
            bf16x8 b1 = *(const bf16x8*)&ks[(ct * 16 + lr) * 64 + sw1];
            f32x4 acc = __builtin_amdgcn_mfma_f32_16x16x32_bf16(aq0, b0, zz, 0, 0, 0);
            acc = __builtin_amdgcn_mfma_f32_16x16x32_bf16(aq1, b1, acc, 0, 0, 0);
            s[ct] = acc;
        }
        __builtin_amdgcn_s_setprio(0);

        // ---- fixed-max softmax numerator: p = exp2(s - 12), packed to LDS ----
        #pragma unroll
        for (int r = 0; r < 4; r++) {
            int q = lg * 4 + r;
            int base = q * 64;
            int sz = (q & 7) << 3;
            float p0 = exp2f(s[0][r] - 12.f);
            float p1 = exp2f(s[1][r] - 12.f);
            float p2 = exp2f(s[2][r] - 12.f);
            float p3 = exp2f(s[3][r] - 12.f);
            unsigned pk0, pk1;
            asm("v_cvt_pk_bf16_f32 %0, %1, %2" : "=v"(pk0) : "v"(p0), "v"(p1));
            asm("v_cvt_pk_bf16_f32 %0, %1, %2" : "=v"(pk1) : "v"(p2), "v"(p3));
            Ps[w][base + ((lr)      ^ sz)] = (u16)pk0;
            Ps[w][base + ((16 + lr) ^ sz)] = (u16)(pk0 >> 16);
            Ps[w][base + ((32 + lr) ^ sz)] = (u16)pk1;
            Ps[w][base + ((48 + lr) ^ sz)] = (u16)(pk1 >> 16);
        }
        asm volatile("s_waitcnt lgkmcnt(0)" ::: "memory");
        __builtin_amdgcn_sched_barrier(0);

        // ---- PV (+ l via ones-row tile ct=4) ----
        __builtin_amdgcn_s_setprio(1);
        #pragma unroll
        for (int kk = 0; kk < 2; kk++) {
            const int sw = kk ? sw1 : sw0;
            bf16x8 pa = *(const bf16x8*)&Ps[w][lr * 64 + sw];
            #pragma unroll
            for (int ct = 0; ct < 5; ct++) {
                bf16x8 bv = *(const bf16x8*)&vs[(ct * 16 + lr) * 64 + sw];
                o[ct] = __builtin_amdgcn_mfma_f32_16x16x32_bf16(pa, bv, o[ct], 0, 0, 0);
            }
        }
        __builtin_amdgcn_s_setprio(0);

        // ---- write next tile from regs, barrier, issue loads for t+2 ----
        if (t < 31) {
            u16* kd = Ks[(t + 1) & 1];
            u16* vd = Vs[(t + 1) & 1];
            *(uint4*)&kd[se0] = ka;  *(uint4*)&kd[se1] = kb;
            *(uint4*)&vd[se0] = va;  *(uint4*)&vd[se1] = vb;
        }
        __syncthreads();
        if (t < 30) {
            int kt = kt0 + t + 2;
            ka = *(const uint4*)(Kbase + (size_t)kt * 8192);
            kb = *(const uint4*)(Kbase + (size_t)kt * 8192 + 16);
            va = *(const uint4*)(Vbase + kt * 128);
            vb = *(const uint4*)(Vbase + kt * 128 + 16);
        }
    }

    // ---- epilogue: unnormalized partial O (bf16) + l (fp32, from ones-row tile) ----
    u16* op = Opart + (size_t)sp * ((size_t)B_ * N_ * C_)
            + ((size_t)(b * N_ + qt * 64 + w * 16)) * C_;
    #pragma unroll
    for (int r = 0; r < 4; r++)
        #pragma unroll
        for (int ct = 0; ct < 4; ct++)
            op[(lg * 4 + r) * C_ + ct * 16 + lr] = f2bf(o[ct][r]);
    if (lr == 0) {
        float* mlp = ml + (size_t)sp * (B_ * N_) + b * N_ + qt * 64 + w * 16 + lg * 4;
        #pragma unroll
        for (int r = 0; r < 4; r++) mlp[r] = o[4][r];
    }
}

// ---------------- Kernel 4: fused combine + output projection + residual ----------------
__global__ __launch_bounds__(256) void proj_kernel(
    const u16* __restrict__ Opart, const float* __restrict__ ml,
    const float* __restrict__ Wp, const float* __restrict__ bp,
    const float* __restrict__ x, float* __restrict__ out) {
    __shared__ __align__(16) u16 wp[64][64];
    __shared__ __align__(16) u16 og[64][64];
    const int b = blockIdx.x >> 6;
    const int nt = blockIdx.x & 63;
    const int tid = threadIdx.x;

    {   // stage Wp bf16 swizzled
        const int rw = tid >> 2, qd = tid & 3;
        const float4* wsrc = (const float4*)(Wp + rw * 64 + qd * 16);
        float4 f0 = wsrc[0], f1 = wsrc[1], f2 = wsrc[2], f3 = wsrc[3];
        u16 pk[16];
        pk[0]=f2bf(f0.x); pk[1]=f2bf(f0.y); pk[2]=f2bf(f0.z); pk[3]=f2bf(f0.w);
        pk[4]=f2bf(f1.x); pk[5]=f2bf(f1.y); pk[6]=f2bf(f1.z); pk[7]=f2bf(f1.w);
        pk[8]=f2bf(f2.x); pk[9]=f2bf(f2.y); pk[10]=f2bf(f2.z); pk[11]=f2bf(f2.w);
        pk[12]=f2bf(f3.x); pk[13]=f2bf(f3.y); pk[14]=f2bf(f3.z); pk[15]=f2bf(f3.w);
        int blk0 = (2 * qd) ^ (rw & 7), blk1 = (2 * qd + 1) ^ (rw & 7);
        *(uint4*)&wp[rw][blk0 * 8] = *(uint4*)&pk[0];
        *(uint4*)&wp[rw][blk1 * 8] = *(uint4*)&pk[8];
    }
    {   // stage O tile: combine the two KV-split partials, normalize by l0+l1
        #pragma unroll
        for (int k2 = 0; k2 < 2; k2++) {
            int cidx = tid + k2 * 256;
            int px = cidx >> 3, blk = cidx & 7;
            int gpix = b * N_ + nt * 64 + px;
            float inv = 1.f / (ml[gpix] + ml[16384 + gpix]);
            u16 o0[8], o1[8], y[8];
            *(uint4*)o0 = *(const uint4*)(Opart + (size_t)gpix * 64 + blk * 8);
            *(uint4*)o1 = *(const uint4*)(Opart + 1048576 + (size_t)gpix * 64 + blk * 8);
            #pragma unroll
            for (int j = 0; j < 8; j++)
                y[j] = f2bf((bf2f(o0[j]) + bf2f(o1[j])) * inv);
            *(uint4*)&og[px][(blk ^ (px & 7)) * 8] = *(uint4*)y;
        }
    }
    __syncthreads();

    const int lane = tid & 63, w = tid >> 6;
    const int lr = lane & 15, lg = lane >> 4;
    const f32x4 zz = {0.f, 0.f, 0.f, 0.f};
    const int sa0 = (lg ^ (lr & 7)) * 8, sa1 = ((4 | lg) ^ (lr & 7)) * 8;

    bf16x8 a0 = *(const bf16x8*)&wp[w * 16 + lr][sa0];
    bf16x8 a1 = *(const bf16x8*)&wp[w * 16 + lr][sa1];
    float bias[4];
    #pragma unroll
    for (int r = 0; r < 4; r++) bias[r] = bp[w * 16 + lg * 4 + r];

    #pragma unroll
    for (int pt = 0; pt < 4; pt++) {
        bf16x8 b0 = *(const bf16x8*)&og[pt * 16 + lr][sa0];
        bf16x8 b1 = *(const bf16x8*)&og[pt * 16 + lr][sa1];
        f32x4 acc = __builtin_amdgcn_mfma_f32_16x16x32_bf16(a0, b0, zz, 0, 0, 0);
        acc = __builtin_amdgcn_mfma_f32_16x16x32_bf16(a1, b1, acc, 0, 0, 0);
        #pragma unroll
        for (int r = 0; r < 4; r++) {
            int cout = w * 16 + lg * 4 + r;
            int px = pt * 16 + lr;
            size_t idx = ((size_t)(b * 64 + cout)) * N_ + nt * 64 + px;
            out[idx] = x[idx] + bias[r] + acc[r];
        }
    }
}

extern "C" void kernel_launch(void* const* d_in, const int* in_sizes, int n_in,
                              void* d_out, int out_size, void* d_ws, size_t ws_size,
                              hipStream_t stream) {
    const float* x     = (const float*)d_in[0];
    const float* gamma = (const float*)d_in[1];
    const float* beta  = (const float*)d_in[2];
    const float* Wq    = (const float*)d_in[3];
    const float* bq    = (const float*)d_in[4];
    const float* Wk    = (const float*)d_in[5];
    const float* bk    = (const float*)d_in[6];
    const float* Wv    = (const float*)d_in[7];
    const float* bv    = (const float*)d_in[8];
    const float* Wp    = (const float*)d_in[9];
    const float* bp    = (const float*)d_in[10];
    float* out = (float*)d_out;

    const size_t elems = (size_t)B_ * N_ * C_;           // 1M
    float* partials = (float*)d_ws;                      // 4 KB
    float* ml = (float*)((char*)d_ws + 4096);            // 2*16384 f32 = 128 KB
    u16* Qb = (u16*)((char*)d_ws + 4096 + 131072);
    u16* Kb = Qb + elems;
    u16* Vt = Kb + elems;
    u16* Opart = Vt + elems;                             // 2 splits * 2 MB = 4 MB

    gn_reduce<<<256, 256, 0, stream>>>(x, partials);
    qkv_kernel<<<256, 256, 0, stream>>>(x, gamma, beta, partials,
                                        Wq, bq, Wk, bk, Wv, bv, Qb, Kb, Vt);
    flash_kernel<<<512, 256, 0, stream>>>(Qb, Kb, Vt, Opart, ml);
    proj_kernel<<<256, 256, 0, stream>>>(Opart, ml, Wp, bp, x, out);
}

// Round 5
// 58.603 us; speedup vs baseline: 2.8729x; 1.0841x over previous
//
#include <hip/hip_runtime.h>
#include <math.h>

#define B_ 4
#define C_ 64
#define N_ 4096

typedef unsigned short u16;
typedef __attribute__((ext_vector_type(8))) short bf16x8;
typedef __attribute__((ext_vector_type(4))) float f32x4;

__device__ __forceinline__ u16 f2bf(float f) {
    unsigned u = __float_as_uint(f);
    u += 0x7fff + ((u >> 16) & 1);
    return (u16)(u >> 16);
}
__device__ __forceinline__ float bf2f(u16 h) {
    return __uint_as_float(((unsigned)h) << 16);
}

// ---------------- Kernel 1: GroupNorm partial reduction ----------------
__global__ __launch_bounds__(256) void gn_reduce(const float* __restrict__ x,
                                                 float* __restrict__ partials) {
    int bg = blockIdx.x >> 3, chunk = blockIdx.x & 7;
    const float4* xv = (const float4*)(x + (size_t)bg * 32768 + (size_t)chunk * 4096);
    float s = 0.f, ss = 0.f;
    #pragma unroll
    for (int k = 0; k < 4; k++) {
        float4 v = xv[threadIdx.x + 256 * k];
        s += v.x + v.y + v.z + v.w;
        ss += v.x * v.x + v.y * v.y + v.z * v.z + v.w * v.w;
    }
    #pragma unroll
    for (int off = 1; off < 64; off <<= 1) {
        s += __shfl_xor(s, off);
        ss += __shfl_xor(ss, off);
    }
    __shared__ float red[2][4];
    int w = threadIdx.x >> 6;
    if ((threadIdx.x & 63) == 0) { red[0][w] = s; red[1][w] = ss; }
    __syncthreads();
    if (threadIdx.x == 0) {
        s = red[0][0] + red[0][1] + red[0][2] + red[0][3];
        ss = red[1][0] + red[1][1] + red[1][2] + red[1][3];
        partials[bg * 16 + chunk * 2] = s;
        partials[bg * 16 + chunk * 2 + 1] = ss;
    }
}

// ---------------- Kernel 2: fused GroupNorm-apply + QKV projections (MFMA) ----------------
__global__ __launch_bounds__(256) void qkv_kernel(
    const float* __restrict__ x, const float* __restrict__ gamma,
    const float* __restrict__ beta, const float* __restrict__ partials,
    const float* __restrict__ Wq, const float* __restrict__ bq,
    const float* __restrict__ Wk, const float* __restrict__ bk,
    const float* __restrict__ Wv, const float* __restrict__ bv,
    u16* __restrict__ Qo, u16* __restrict__ Ko, u16* __restrict__ Vt) {
    __shared__ __align__(16) u16 wt[3][64][64];
    __shared__ __align__(16) u16 xs[64][64];
    __shared__ __align__(16) u16 odt[64][72];

    const int b = blockIdx.x >> 6;
    const int nt = blockIdx.x & 63;
    const int tid = threadIdx.x;
    const float* Ws[3] = {Wq, Wk, Wv};
    const float* bs[3] = {bq, bk, bv};

    {   // stage weights: fp32 -> bf16, swizzled (block ^= row&7)
        const int rw = tid >> 2, qd = tid & 3;
        #pragma unroll
        for (int s = 0; s < 3; s++) {
            const float4* wsrc = (const float4*)(Ws[s] + rw * 64 + qd * 16);
            float4 f0 = wsrc[0], f1 = wsrc[1], f2 = wsrc[2], f3 = wsrc[3];
            u16 pk[16];
            pk[0]=f2bf(f0.x); pk[1]=f2bf(f0.y); pk[2]=f2bf(f0.z); pk[3]=f2bf(f0.w);
            pk[4]=f2bf(f1.x); pk[5]=f2bf(f1.y); pk[6]=f2bf(f1.z); pk[7]=f2bf(f1.w);
            pk[8]=f2bf(f2.x); pk[9]=f2bf(f2.y); pk[10]=f2bf(f2.z); pk[11]=f2bf(f2.w);
            pk[12]=f2bf(f3.x); pk[13]=f2bf(f3.y); pk[14]=f2bf(f3.z); pk[15]=f2bf(f3.w);
            int blk0 = (2 * qd) ^ (rw & 7), blk1 = (2 * qd + 1) ^ (rw & 7);
            *(uint4*)&wt[s][rw][blk0 * 8] = *(uint4*)&pk[0];
            *(uint4*)&wt[s][rw][blk1 * 8] = *(uint4*)&pk[8];
        }
    }
    {   // GN-apply + stage xn tile
        const int c = tid >> 2, px0 = (tid & 3) * 16;
        const int g = c >> 3, bg = b * 8 + g;
        float s = 0.f, ss = 0.f;
        #pragma unroll
        for (int i = 0; i < 8; i++) {
            s += partials[bg * 16 + i * 2];
            ss += partials[bg * 16 + i * 2 + 1];
        }
        float mean = s * (1.f / 32768.f);
        float var = ss * (1.f / 32768.f) - mean * mean;
        float rstd = rsqrtf(var + 1e-5f);
        float ga = gamma[c] * rstd;
        float bb = beta[c] - mean * ga;
        const float4* xp = (const float4*)(x + ((size_t)(b * 64 + c)) * N_ + nt * 64 + px0);
        float4 q0 = xp[0], q1 = xp[1], q2 = xp[2], q3 = xp[3];
        float vals[16] = {q0.x,q0.y,q0.z,q0.w, q1.x,q1.y,q1.z,q1.w,
                          q2.x,q2.y,q2.z,q2.w, q3.x,q3.y,q3.z,q3.w};
        #pragma unroll
        for (int e = 0; e < 16; e++) {
            int px = px0 + e;
            xs[px][((c >> 3) ^ (px & 7)) * 8 + (c & 7)] = f2bf(vals[e] * ga + bb);
        }
    }
    __syncthreads();

    const int lane = tid & 63, w = tid >> 6;
    const int lr = lane & 15, lg = lane >> 4;
    const f32x4 zz = {0.f, 0.f, 0.f, 0.f};
    const int sa0 = (lg ^ (lr & 7)) * 8, sa1 = ((4 | lg) ^ (lr & 7)) * 8;

    #pragma unroll
    for (int s = 0; s < 3; s++) {
        bf16x8 a0 = *(const bf16x8*)&wt[s][w * 16 + lr][sa0];
        bf16x8 a1 = *(const bf16x8*)&wt[s][w * 16 + lr][sa1];
        float bias[4];
        #pragma unroll
        for (int r = 0; r < 4; r++) bias[r] = bs[s][w * 16 + lg * 4 + r];
        #pragma unroll
        for (int pt = 0; pt < 4; pt++) {
            bf16x8 b0 = *(const bf16x8*)&xs[pt * 16 + lr][sa0];
            bf16x8 b1 = *(const bf16x8*)&xs[pt * 16 + lr][sa1];
            f32x4 acc = __builtin_amdgcn_mfma_f32_16x16x32_bf16(a0, b0, zz, 0, 0, 0);
            acc = __builtin_amdgcn_mfma_f32_16x16x32_bf16(a1, b1, acc, 0, 0, 0);
            if (s == 0) {
                #pragma unroll
                for (int r = 0; r < 4; r++)
                    odt[pt * 16 + lr][w * 16 + lg * 4 + r] = f2bf((acc[r] + bias[r]) * 0.18033688f);
            } else if (s == 1) {
                #pragma unroll
                for (int r = 0; r < 4; r++)
                    odt[pt * 16 + lr][w * 16 + lg * 4 + r] = f2bf(acc[r] + bias[r]);
            } else {
                #pragma unroll
                for (int r = 0; r < 4; r++)
                    odt[w * 16 + lg * 4 + r][pt * 16 + lr] = f2bf(acc[r] + bias[r]);
            }
        }
        __syncthreads();
        if (s < 2) {
            u16* dst = (s == 0 ? Qo : Ko) + ((size_t)(b * N_ + nt * 64)) * 64;
            #pragma unroll
            for (int k2 = 0; k2 < 2; k2++) {
                int c = tid + k2 * 256;
                int px = c >> 3, blk = c & 7;
                *(uint4*)(dst + (size_t)px * 64 + blk * 8) = *(const uint4*)&odt[px][blk * 8];
            }
        } else {
            #pragma unroll
            for (int k2 = 0; k2 < 2; k2++) {
                int c = tid + k2 * 256;
                int co = c >> 3, blk = c & 7;
                *(uint4*)(Vt + ((size_t)(b * 64 + co)) * N_ + nt * 64 + blk * 8) =
                    *(const uint4*)&odt[co][blk * 8];
            }
        }
        __syncthreads();
    }
}

// ---------------- Kernel 3: flash attention, fixed-max softmax, KV-split xN ----------------
// grid = nsplit*256; sp = bid>>8. Fixed M=12 (exp2 domain); l via ones-row MFMA tile.
__global__ __launch_bounds__(256) void flash_kernel(
    const u16* __restrict__ Qg, const u16* __restrict__ Kg,
    const u16* __restrict__ Vg, u16* __restrict__ Opart, float* __restrict__ ml,
    int nsplit) {
    __shared__ __align__(16) u16 Ks[2][4096];
    __shared__ __align__(16) u16 Vs[2][5120];   // rows 0..63 = V^T; 64 = ones; 65..79 = 0
    __shared__ __align__(16) u16 Ps[4][1024];

    const int sp = blockIdx.x >> 8;
    const int b  = (blockIdx.x >> 6) & 3;
    const int qt = blockIdx.x & 63;
    const int tid = threadIdx.x;
    const int w = tid >> 6, lane = tid & 63;
    const int lr = lane & 15, lg = lane >> 4;

    const int per = (nsplit == 3) ? 22 : 32;
    const int kt0 = sp * per;
    const int NT = min(per, 64 - kt0);   // 22/22/20 or 32/32 (always even)

    // constant ones/zeros rows for both buffers
    for (int i = tid; i < 2048; i += 256) {
        int bufi = i >> 10, off = i & 1023;
        Vs[bufi][4096 + off] = (off < 64) ? (u16)0x3F80 : (u16)0;
    }

    const u16* qrow = Qg + ((size_t)(b * N_ + qt * 64 + w * 16 + lr)) * C_;
    bf16x8 aq0 = *(const bf16x8*)(qrow + lg * 8);
    bf16x8 aq1 = *(const bf16x8*)(qrow + 32 + lg * 8);

    const int srow = tid >> 2;
    const int scb  = (tid & 3) * 32;
    const char* Kbase = (const char*)(Kg + (size_t)b * N_ * C_) + (size_t)srow * 128 + scb;
    const char* Vbase = (const char*)(Vg + (size_t)b * C_ * N_) + (size_t)srow * (N_ * 2) + scb;
    const int se0 = srow * 64 + (((scb)      ^ ((srow & 7) << 4)) >> 1);
    const int se1 = srow * 64 + (((scb + 16) ^ ((srow & 7) << 4)) >> 1);

    const int sw0 = ((lg ^ (lr & 7)) << 3);
    const int sw1 = (((4 | lg) ^ (lr & 7)) << 3);

    // hoisted P-store addresses (loop-invariant)
    u16* pswr[4][4];
    #pragma unroll
    for (int r = 0; r < 4; r++) {
        int q = lg * 4 + r, sz = (q & 7) << 3;
        #pragma unroll
        for (int ct = 0; ct < 4; ct++)
            pswr[r][ct] = &Ps[w][q * 64 + ((ct * 16 + lr) ^ sz)];
    }

    {   // prologue: tile kt0 -> LDS[0]
        uint4 k0a = *(const uint4*)(Kbase + (size_t)kt0 * 8192);
        uint4 k0b = *(const uint4*)(Kbase + (size_t)kt0 * 8192 + 16);
        uint4 v0a = *(const uint4*)(Vbase + kt0 * 128);
        uint4 v0b = *(const uint4*)(Vbase + kt0 * 128 + 16);
        *(uint4*)&Ks[0][se0] = k0a;  *(uint4*)&Ks[0][se1] = k0b;
        *(uint4*)&Vs[0][se0] = v0a;  *(uint4*)&Vs[0][se1] = v0b;
    }
    uint4 ka = *(const uint4*)(Kbase + (size_t)(kt0 + 1) * 8192);
    uint4 kb = *(const uint4*)(Kbase + (size_t)(kt0 + 1) * 8192 + 16);
    uint4 va = *(const uint4*)(Vbase + (kt0 + 1) * 128);
    uint4 vb = *(const uint4*)(Vbase + (kt0 + 1) * 128 + 16);
    __syncthreads();

    f32x4 zz = {0.f, 0.f, 0.f, 0.f};
    f32x4 o[5];
    #pragma unroll
    for (int ct = 0; ct < 5; ct++) o[ct] = zz;

    auto body = [&](int t, int bi) {
        const u16* ks = Ks[bi];
        const u16* vs = Vs[bi];

        // ---- QK^T ----
        f32x4 s[4];
        __builtin_amdgcn_s_setprio(1);
        #pragma unroll
        for (int ct = 0; ct < 4; ct++) {
            bf16x8 b0 = *(const bf16x8*)&ks[(ct * 16 + lr) * 64 + sw0];
            bf16x8 b1 = *(const bf16x8*)&ks[(ct * 16 + lr) * 64 + sw1];
            f32x4 acc = __builtin_amdgcn_mfma_f32_16x16x32_bf16(aq0, b0, zz, 0, 0, 0);
            acc = __builtin_amdgcn_mfma_f32_16x16x32_bf16(aq1, b1, acc, 0, 0, 0);
            s[ct] = acc;
        }
        __builtin_amdgcn_s_setprio(0);

        // ---- fixed-max softmax numerator: p = exp2(s - 12), packed to LDS ----
        #pragma unroll
        for (int r = 0; r < 4; r++) {
            float p0 = exp2f(s[0][r] - 12.f);
            float p1 = exp2f(s[1][r] - 12.f);
            float p2 = exp2f(s[2][r] - 12.f);
            float p3 = exp2f(s[3][r] - 12.f);
            unsigned pk0, pk1;
            asm("v_cvt_pk_bf16_f32 %0, %1, %2" : "=v"(pk0) : "v"(p0), "v"(p1));
            asm("v_cvt_pk_bf16_f32 %0, %1, %2" : "=v"(pk1) : "v"(p2), "v"(p3));
            *pswr[r][0] = (u16)pk0;
            *pswr[r][1] = (u16)(pk0 >> 16);
            *pswr[r][2] = (u16)pk1;
            *pswr[r][3] = (u16)(pk1 >> 16);
        }
        asm volatile("s_waitcnt lgkmcnt(0)" ::: "memory");

        // ---- PV (+ l via ones-row tile ct=4) ----
        __builtin_amdgcn_s_setprio(1);
        #pragma unroll
        for (int kk = 0; kk < 2; kk++) {
            const int sw = kk ? sw1 : sw0;
            bf16x8 pa = *(const bf16x8*)&Ps[w][lr * 64 + sw];
            #pragma unroll
            for (int ct = 0; ct < 5; ct++) {
                bf16x8 bv = *(const bf16x8*)&vs[(ct * 16 + lr) * 64 + sw];
                o[ct] = __builtin_amdgcn_mfma_f32_16x16x32_bf16(pa, bv, o[ct], 0, 0, 0);
            }
        }
        __builtin_amdgcn_s_setprio(0);

        // ---- write next tile from regs, barrier, issue loads for t+2 ----
        if (t < NT - 1) {
            u16* kd = Ks[bi ^ 1];
            u16* vd = Vs[bi ^ 1];
            *(uint4*)&kd[se0] = ka;  *(uint4*)&kd[se1] = kb;
            *(uint4*)&vd[se0] = va;  *(uint4*)&vd[se1] = vb;
        }
        __syncthreads();
        if (t < NT - 2) {
            int kt = kt0 + t + 2;
            ka = *(const uint4*)(Kbase + (size_t)kt * 8192);
            kb = *(const uint4*)(Kbase + (size_t)kt * 8192 + 16);
            va = *(const uint4*)(Vbase + kt * 128);
            vb = *(const uint4*)(Vbase + kt * 128 + 16);
        }
    };
    for (int tt = 0; tt < NT; tt += 2) { body(tt, 0); body(tt + 1, 1); }

    // ---- epilogue: unnormalized partial O (bf16) + l (fp32) ----
    u16* op = Opart + (size_t)sp * 1048576
            + ((size_t)(b * N_ + qt * 64 + w * 16)) * C_;
    #pragma unroll
    for (int r = 0; r < 4; r++)
        #pragma unroll
        for (int ct = 0; ct < 4; ct++)
            op[(lg * 4 + r) * C_ + ct * 16 + lr] = f2bf(o[ct][r]);
    if (lr == 0) {
        float* mlp = ml + (size_t)sp * 16384 + b * N_ + qt * 64 + w * 16 + lg * 4;
        #pragma unroll
        for (int r = 0; r < 4; r++) mlp[r] = o[4][r];
    }
}

// ---------------- Kernel 4: fused combine + output projection + residual ----------------
__global__ __launch_bounds__(256) void proj_kernel(
    const u16* __restrict__ Opart, const float* __restrict__ ml,
    const float* __restrict__ Wp, const float* __restrict__ bp,
    const float* __restrict__ x, float* __restrict__ out, int nsplit) {
    __shared__ __align__(16) u16 wp[64][64];
    __shared__ __align__(16) u16 og[64][64];
    const int b = blockIdx.x >> 6;
    const int nt = blockIdx.x & 63;
    const int tid = threadIdx.x;

    {   // stage Wp bf16 swizzled
        const int rw = tid >> 2, qd = tid & 3;
        const float4* wsrc = (const float4*)(Wp + rw * 64 + qd * 16);
        float4 f0 = wsrc[0], f1 = wsrc[1], f2 = wsrc[2], f3 = wsrc[3];
        u16 pk[16];
        pk[0]=f2bf(f0.x); pk[1]=f2bf(f0.y); pk[2]=f2bf(f0.z); pk[3]=f2bf(f0.w);
        pk[4]=f2bf(f1.x); pk[5]=f2bf(f1.y); pk[6]=f2bf(f1.z); pk[7]=f2bf(f1.w);
        pk[8]=f2bf(f2.x); pk[9]=f2bf(f2.y); pk[10]=f2bf(f2.z); pk[11]=f2bf(f2.w);
        pk[12]=f2bf(f3.x); pk[13]=f2bf(f3.y); pk[14]=f2bf(f3.z); pk[15]=f2bf(f3.w);
        int blk0 = (2 * qd) ^ (rw & 7), blk1 = (2 * qd + 1) ^ (rw & 7);
        *(uint4*)&wp[rw][blk0 * 8] = *(uint4*)&pk[0];
        *(uint4*)&wp[rw][blk1 * 8] = *(uint4*)&pk[8];
    }
    {   // stage O tile: combine nsplit partials, normalize by sum of l
        #pragma unroll
        for (int k2 = 0; k2 < 2; k2++) {
            int cidx = tid + k2 * 256;
            int px = cidx >> 3, blk = cidx & 7;
            int gpix = b * N_ + nt * 64 + px;
            float lsum = 0.f;
            for (int s = 0; s < nsplit; s++) lsum += ml[(size_t)s * 16384 + gpix];
            float inv = 1.f / lsum;
            float acc8[8] = {0.f,0.f,0.f,0.f,0.f,0.f,0.f,0.f};
            for (int s = 0; s < nsplit; s++) {
                u16 ov[8];
                *(uint4*)ov = *(const uint4*)(Opart + (size_t)s * 1048576 + (size_t)gpix * 64 + blk * 8);
                #pragma unroll
                for (int j = 0; j < 8; j++) acc8[j] += bf2f(ov[j]);
            }
            u16 y[8];
            #pragma unroll
            for (int j = 0; j < 8; j++) y[j] = f2bf(acc8[j] * inv);
            *(uint4*)&og[px][(blk ^ (px & 7)) * 8] = *(uint4*)y;
        }
    }
    __syncthreads();

    const int lane = tid & 63, w = tid >> 6;
    const int lr = lane & 15, lg = lane >> 4;
    const f32x4 zz = {0.f, 0.f, 0.f, 0.f};
    const int sa0 = (lg ^ (lr & 7)) * 8, sa1 = ((4 | lg) ^ (lr & 7)) * 8;

    bf16x8 a0 = *(const bf16x8*)&wp[w * 16 + lr][sa0];
    bf16x8 a1 = *(const bf16x8*)&wp[w * 16 + lr][sa1];
    float bias[4];
    #pragma unroll
    for (int r = 0; r < 4; r++) bias[r] = bp[w * 16 + lg * 4 + r];

    #pragma unroll
    for (int pt = 0; pt < 4; pt++) {
        bf16x8 b0 = *(const bf16x8*)&og[pt * 16 + lr][sa0];
        bf16x8 b1 = *(const bf16x8*)&og[pt * 16 + lr][sa1];
        f32x4 acc = __builtin_amdgcn_mfma_f32_16x16x32_bf16(a0, b0, zz, 0, 0, 0);
        acc = __builtin_amdgcn_mfma_f32_16x16x32_bf16(a1, b1, acc, 0, 0, 0);
        #pragma unroll
        for (int r = 0; r < 4; r++) {
            int cout = w * 16 + lg * 4 + r;
            int px = pt * 16 + lr;
            size_t idx = ((size_t)(b * 64 + cout)) * N_ + nt * 64 + px;
            out[idx] = x[idx] + bias[r] + acc[r];
        }
    }
}

extern "C" void kernel_launch(void* const* d_in, const int* in_sizes, int n_in,
                              void* d_out, int out_size, void* d_ws, size_t ws_size,
                              hipStream_t stream) {
    const float* x     = (const float*)d_in[0];
    const float* gamma = (const float*)d_in[1];
    const float* beta  = (const float*)d_in[2];
    const float* Wq    = (const float*)d_in[3];
    const float* bq    = (const float*)d_in[4];
    const float* Wk    = (const float*)d_in[5];
    const float* bk    = (const float*)d_in[6];
    const float* Wv    = (const float*)d_in[7];
    const float* bv    = (const float*)d_in[8];
    const float* Wp    = (const float*)d_in[9];
    const float* bp    = (const float*)d_in[10];
    float* out = (float*)d_out;

    const size_t elems = (size_t)B_ * N_ * C_;           // 1M
    // layout: partials 4KB | ml 192KB | Qb 2MB | Kb 2MB | Vt 2MB | Opart 6MB
    float* partials = (float*)d_ws;
    float* ml = (float*)((char*)d_ws + 4096);
    u16* Qb = (u16*)((char*)d_ws + 4096 + 196608);
    u16* Kb = Qb + elems;
    u16* Vt = Kb + elems;
    u16* Opart = Vt + elems;

    const size_t need3 = 4096 + 196608 + 3 * elems * 2 + 3 * elems * 2;
    const int nsplit = (ws_size >= need3) ? 3 : 2;

    gn_reduce<<<256, 256, 0, stream>>>(x, partials);
    qkv_kernel<<<256, 256, 0, stream>>>(x, gamma, beta, partials,
                                        Wq, bq, Wk, bk, Wv, bv, Qb, Kb, Vt);
    flash_kernel<<<nsplit * 256, 256, 0, stream>>>(Qb, Kb, Vt, Opart, ml, nsplit);
    proj_kernel<<<256, 256, 0, stream>>>(Opart, ml, Wp, bp, x, out, nsplit);
}

// Round 6
// 54.658 us; speedup vs baseline: 3.0802x; 1.0722x over previous
//
#include <hip/hip_runtime.h>
#include <math.h>

#define B_ 4
#define C_ 64
#define N_ 4096

typedef unsigned short u16;
typedef __attribute__((ext_vector_type(8))) short bf16x8;
typedef __attribute__((ext_vector_type(4))) float f32x4;
typedef __attribute__((ext_vector_type(16))) float f32x16;
typedef __attribute__((ext_vector_type(2))) int i32x2;

__device__ __forceinline__ u16 f2bf(float f) {
    unsigned u = __float_as_uint(f);
    u += 0x7fff + ((u >> 16) & 1);
    return (u16)(u >> 16);
}
__device__ __forceinline__ float bf2f(u16 h) {
    return __uint_as_float(((unsigned)h) << 16);
}

// ---------------- Kernel 1: GroupNorm partial reduction ----------------
__global__ __launch_bounds__(256) void gn_reduce(const float* __restrict__ x,
                                                 float* __restrict__ partials) {
    int bg = blockIdx.x >> 3, chunk = blockIdx.x & 7;
    const float4* xv = (const float4*)(x + (size_t)bg * 32768 + (size_t)chunk * 4096);
    float s = 0.f, ss = 0.f;
    #pragma unroll
    for (int k = 0; k < 4; k++) {
        float4 v = xv[threadIdx.x + 256 * k];
        s += v.x + v.y + v.z + v.w;
        ss += v.x * v.x + v.y * v.y + v.z * v.z + v.w * v.w;
    }
    #pragma unroll
    for (int off = 1; off < 64; off <<= 1) {
        s += __shfl_xor(s, off);
        ss += __shfl_xor(ss, off);
    }
    __shared__ float red[2][4];
    int w = threadIdx.x >> 6;
    if ((threadIdx.x & 63) == 0) { red[0][w] = s; red[1][w] = ss; }
    __syncthreads();
    if (threadIdx.x == 0) {
        s = red[0][0] + red[0][1] + red[0][2] + red[0][3];
        ss = red[1][0] + red[1][1] + red[1][2] + red[1][3];
        partials[bg * 16 + chunk * 2] = s;
        partials[bg * 16 + chunk * 2 + 1] = ss;
    }
}

// ---------------- Kernel 2: fused GroupNorm-apply + QKV projections (MFMA) ----------------
__global__ __launch_bounds__(256) void qkv_kernel(
    const float* __restrict__ x, const float* __restrict__ gamma,
    const float* __restrict__ beta, const float* __restrict__ partials,
    const float* __restrict__ Wq, const float* __restrict__ bq,
    const float* __restrict__ Wk, const float* __restrict__ bk,
    const float* __restrict__ Wv, const float* __restrict__ bv,
    u16* __restrict__ Qo, u16* __restrict__ Ko, u16* __restrict__ Vt) {
    __shared__ __align__(16) u16 wt[3][64][64];
    __shared__ __align__(16) u16 xs[64][64];
    __shared__ __align__(16) u16 odt[64][72];

    const int b = blockIdx.x >> 6;
    const int nt = blockIdx.x & 63;
    const int tid = threadIdx.x;
    const float* Ws[3] = {Wq, Wk, Wv};
    const float* bs[3] = {bq, bk, bv};

    {   // stage weights: fp32 -> bf16, swizzled (block ^= row&7)
        const int rw = tid >> 2, qd = tid & 3;
        #pragma unroll
        for (int s = 0; s < 3; s++) {
            const float4* wsrc = (const float4*)(Ws[s] + rw * 64 + qd * 16);
            float4 f0 = wsrc[0], f1 = wsrc[1], f2 = wsrc[2], f3 = wsrc[3];
            u16 pk[16];
            pk[0]=f2bf(f0.x); pk[1]=f2bf(f0.y); pk[2]=f2bf(f0.z); pk[3]=f2bf(f0.w);
            pk[4]=f2bf(f1.x); pk[5]=f2bf(f1.y); pk[6]=f2bf(f1.z); pk[7]=f2bf(f1.w);
            pk[8]=f2bf(f2.x); pk[9]=f2bf(f2.y); pk[10]=f2bf(f2.z); pk[11]=f2bf(f2.w);
            pk[12]=f2bf(f3.x); pk[13]=f2bf(f3.y); pk[14]=f2bf(f3.z); pk[15]=f2bf(f3.w);
            int blk0 = (2 * qd) ^ (rw & 7), blk1 = (2 * qd + 1) ^ (rw & 7);
            *(uint4*)&wt[s][rw][blk0 * 8] = *(uint4*)&pk[0];
            *(uint4*)&wt[s][rw][blk1 * 8] = *(uint4*)&pk[8];
        }
    }
    {   // GN-apply + stage xn tile
        const int c = tid >> 2, px0 = (tid & 3) * 16;
        const int g = c >> 3, bg = b * 8 + g;
        float s = 0.f, ss = 0.f;
        #pragma unroll
        for (int i = 0; i < 8; i++) {
            s += partials[bg * 16 + i * 2];
            ss += partials[bg * 16 + i * 2 + 1];
        }
        float mean = s * (1.f / 32768.f);
        float var = ss * (1.f / 32768.f) - mean * mean;
        float rstd = rsqrtf(var + 1e-5f);
        float ga = gamma[c] * rstd;
        float bb = beta[c] - mean * ga;
        const float4* xp = (const float4*)(x + ((size_t)(b * 64 + c)) * N_ + nt * 64 + px0);
        float4 q0 = xp[0], q1 = xp[1], q2 = xp[2], q3 = xp[3];
        float vals[16] = {q0.x,q0.y,q0.z,q0.w, q1.x,q1.y,q1.z,q1.w,
                          q2.x,q2.y,q2.z,q2.w, q3.x,q3.y,q3.z,q3.w};
        #pragma unroll
        for (int e = 0; e < 16; e++) {
            int px = px0 + e;
            xs[px][((c >> 3) ^ (px & 7)) * 8 + (c & 7)] = f2bf(vals[e] * ga + bb);
        }
    }
    __syncthreads();

    const int lane = tid & 63, w = tid >> 6;
    const int lr = lane & 15, lg = lane >> 4;
    const f32x4 zz = {0.f, 0.f, 0.f, 0.f};
    const int sa0 = (lg ^ (lr & 7)) * 8, sa1 = ((4 | lg) ^ (lr & 7)) * 8;

    #pragma unroll
    for (int s = 0; s < 3; s++) {
        bf16x8 a0 = *(const bf16x8*)&wt[s][w * 16 + lr][sa0];
        bf16x8 a1 = *(const bf16x8*)&wt[s][w * 16 + lr][sa1];
        float bias[4];
        #pragma unroll
        for (int r = 0; r < 4; r++) bias[r] = bs[s][w * 16 + lg * 4 + r];
        #pragma unroll
        for (int pt = 0; pt < 4; pt++) {
            bf16x8 b0 = *(const bf16x8*)&xs[pt * 16 + lr][sa0];
            bf16x8 b1 = *(const bf16x8*)&xs[pt * 16 + lr][sa1];
            f32x4 acc = __builtin_amdgcn_mfma_f32_16x16x32_bf16(a0, b0, zz, 0, 0, 0);
            acc = __builtin_amdgcn_mfma_f32_16x16x32_bf16(a1, b1, acc, 0, 0, 0);
            if (s == 0) {
                #pragma unroll
                for (int r = 0; r < 4; r++)
                    odt[pt * 16 + lr][w * 16 + lg * 4 + r] = f2bf((acc[r] + bias[r]) * 0.18033688f);
            } else if (s == 1) {
                #pragma unroll
                for (int r = 0; r < 4; r++)
                    odt[pt * 16 + lr][w * 16 + lg * 4 + r] = f2bf(acc[r] + bias[r]);
            } else {
                #pragma unroll
                for (int r = 0; r < 4; r++)
                    odt[w * 16 + lg * 4 + r][pt * 16 + lr] = f2bf(acc[r] + bias[r]);
            }
        }
        __syncthreads();
        if (s < 2) {
            u16* dst = (s == 0 ? Qo : Ko) + ((size_t)(b * N_ + nt * 64)) * 64;
            #pragma unroll
            for (int k2 = 0; k2 < 2; k2++) {
                int c = tid + k2 * 256;
                int px = c >> 3, blk = c & 7;
                *(uint4*)(dst + (size_t)px * 64 + blk * 8) = *(const uint4*)&odt[px][blk * 8];
            }
        } else {
            #pragma unroll
            for (int k2 = 0; k2 < 2; k2++) {
                int c = tid + k2 * 256;
                int co = c >> 3, blk = c & 7;
                *(uint4*)(Vt + ((size_t)(b * 64 + co)) * N_ + nt * 64 + blk * 8) =
                    *(const uint4*)&odt[co][blk * 8];
            }
        }
        __syncthreads();
    }
}

// ---------------- Kernel 3: flash attention, 32x32 MFMA, in-register softmax ----------------
// grid = nsplit*256. 4 waves: qh = w>>1 (q-half of 64-row tile), kh = w&1 (key-half).
// Swapped QK^T: S^T = mfma(K, Q) -> lane col = q; P stays in registers; PV A-frags
// built via v_cvt_pk_bf16_f32 + permlane32_swap. Fixed max M=12 (exp2 domain).
__global__ __launch_bounds__(256, 4) void flash_kernel(
    const u16* __restrict__ Qg, const u16* __restrict__ Kg,
    const u16* __restrict__ Vg, u16* __restrict__ Opart, float* __restrict__ ml,
    int nsplit) {
    __shared__ __align__(16) u16 smem[16384];   // 32 KB: K dbuf 16K | V dbuf 16K
    u16* const Ksb0 = smem;
    u16* const Ksb1 = smem + 4096;
    u16* const Vsb0 = smem + 8192;
    u16* const Vsb1 = smem + 12288;

    const int sp = blockIdx.x >> 8;
    const int b  = (blockIdx.x >> 6) & 3;
    const int qt = blockIdx.x & 63;
    const int tid = threadIdx.x;
    const int w = tid >> 6, lane = tid & 63;
    const int l31 = lane & 31, lh = lane >> 5;
    const int qh = w >> 1, kh = w & 1;

    const int per = (nsplit == 4) ? 16 : (nsplit == 3) ? 22 : 32;
    const int kt0 = sp * per;
    const int NT = min(per, 64 - kt0);   // always even

    // Q B-fragments (col = q = l31, k = ch): 4 x 16B from the lane's q-row
    const u16* qptr = Qg + ((size_t)(b * N_ + qt * 64 + qh * 32 + l31)) * 64 + lh * 8;
    bf16x8 q0 = *(const bf16x8*)(qptr);
    bf16x8 q1 = *(const bf16x8*)(qptr + 16);
    bf16x8 q2 = *(const bf16x8*)(qptr + 32);
    bf16x8 q3 = *(const bf16x8*)(qptr + 48);

    // staging geometry (row-major 64x64 u16 tiles, XOR-swizzled 16B chunks)
    const int srow = tid >> 2;
    const int scb  = (tid & 3) * 32;
    const char* Kbase = (const char*)(Kg + (size_t)b * N_ * C_) + (size_t)srow * 128 + scb;
    const char* Vbase = (const char*)(Vg + (size_t)b * C_ * N_) + (size_t)srow * (N_ * 2) + scb;
    const int se0 = srow * 64 + (((scb)      ^ ((srow & 7) << 4)) >> 1);
    const int se1 = srow * 64 + (((scb + 16) ^ ((srow & 7) << 4)) >> 1);

    // fragment read offsets (u16 units, swizzle-matched)
    const int key = kh * 32 + l31;
    int kaoff[4];
    #pragma unroll
    for (int s = 0; s < 4; s++)
        kaoff[s] = key * 64 + (((s * 2 + lh) ^ (key & 7)) << 3);
    int vboff[2][2];
    #pragma unroll
    for (int c = 0; c < 2; c++) {
        int ch = c * 32 + l31;
        #pragma unroll
        for (int s = 0; s < 2; s++)
            vboff[c][s] = ch * 64 + (((kh * 4 + s * 2 + lh) ^ (ch & 7)) << 3);
    }

    {   // prologue: tile kt0 -> buffer 0
        uint4 k0a = *(const uint4*)(Kbase + (size_t)kt0 * 8192);
        uint4 k0b = *(const uint4*)(Kbase + (size_t)kt0 * 8192 + 16);
        uint4 v0a = *(const uint4*)(Vbase + kt0 * 128);
        uint4 v0b = *(const uint4*)(Vbase + kt0 * 128 + 16);
        *(uint4*)&Ksb0[se0] = k0a;  *(uint4*)&Ksb0[se1] = k0b;
        *(uint4*)&Vsb0[se0] = v0a;  *(uint4*)&Vsb0[se1] = v0b;
    }
    uint4 ka = *(const uint4*)(Kbase + (size_t)(kt0 + 1) * 8192);
    uint4 kb = *(const uint4*)(Kbase + (size_t)(kt0 + 1) * 8192 + 16);
    uint4 va = *(const uint4*)(Vbase + (kt0 + 1) * 128);
    uint4 vb = *(const uint4*)(Vbase + (kt0 + 1) * 128 + 16);
    __syncthreads();

    f32x16 o0, o1;
    #pragma unroll
    for (int r = 0; r < 16; r++) { o0[r] = 0.f; o1[r] = 0.f; }
    float lsum = 0.f;

    auto body = [&](int t, int bi) {
        const u16* ks = bi ? Ksb1 : Ksb0;
        const u16* vs = bi ? Vsb1 : Vsb0;
        u16* kd = bi ? Ksb0 : Ksb1;
        u16* vd = bi ? Vsb0 : Vsb1;

        // ---- QK^T swapped: st = S^T[key][q], lane col = q ----
        f32x16 st;
        #pragma unroll
        for (int r = 0; r < 16; r++) st[r] = 0.f;
        __builtin_amdgcn_s_setprio(1);
        st = __builtin_amdgcn_mfma_f32_32x32x16_bf16(*(const bf16x8*)&ks[kaoff[0]], q0, st, 0, 0, 0);
        st = __builtin_amdgcn_mfma_f32_32x32x16_bf16(*(const bf16x8*)&ks[kaoff[1]], q1, st, 0, 0, 0);
        st = __builtin_amdgcn_mfma_f32_32x32x16_bf16(*(const bf16x8*)&ks[kaoff[2]], q2, st, 0, 0, 0);
        st = __builtin_amdgcn_mfma_f32_32x32x16_bf16(*(const bf16x8*)&ks[kaoff[3]], q3, st, 0, 0, 0);
        __builtin_amdgcn_s_setprio(0);

        // ---- fixed-max softmax numerator, fully in-register ----
        float p[16];
        #pragma unroll
        for (int r = 0; r < 16; r++) p[r] = exp2f(st[r] - 12.f);
        lsum += (((p[0]+p[1])+(p[2]+p[3])) + ((p[4]+p[5])+(p[6]+p[7])))
              + (((p[8]+p[9])+(p[10]+p[11])) + ((p[12]+p[13])+(p[14]+p[15])));

        // pack to bf16 pairs; reg r -> key (r&3)+8*(r>>2)+4*lh
        unsigned c0,c1,c2,c3,c4,c5,c6,c7;
        asm("v_cvt_pk_bf16_f32 %0, %1, %2" : "=v"(c0) : "v"(p[0]),  "v"(p[1]));
        asm("v_cvt_pk_bf16_f32 %0, %1, %2" : "=v"(c1) : "v"(p[2]),  "v"(p[3]));
        asm("v_cvt_pk_bf16_f32 %0, %1, %2" : "=v"(c2) : "v"(p[4]),  "v"(p[5]));
        asm("v_cvt_pk_bf16_f32 %0, %1, %2" : "=v"(c3) : "v"(p[6]),  "v"(p[7]));
        asm("v_cvt_pk_bf16_f32 %0, %1, %2" : "=v"(c4) : "v"(p[8]),  "v"(p[9]));
        asm("v_cvt_pk_bf16_f32 %0, %1, %2" : "=v"(c5) : "v"(p[10]), "v"(p[11]));
        asm("v_cvt_pk_bf16_f32 %0, %1, %2" : "=v"(c6) : "v"(p[12]), "v"(p[13]));
        asm("v_cvt_pk_bf16_f32 %0, %1, %2" : "=v"(c7) : "v"(p[14]), "v"(p[15]));
        // redistribute halves: A-frag needs lane's 8 consecutive keys
        i32x2 r02 = __builtin_amdgcn_permlane32_swap((int)c0, (int)c2, false, false);
        i32x2 r13 = __builtin_amdgcn_permlane32_swap((int)c1, (int)c3, false, false);
        i32x2 r46 = __builtin_amdgcn_permlane32_swap((int)c4, (int)c6, false, false);
        i32x2 r57 = __builtin_amdgcn_permlane32_swap((int)c5, (int)c7, false, false);
        union U { int u[4]; bf16x8 v; };
        U pa0 = {{r02[0], r13[0], r02[1], r13[1]}};   // keys 0..15 (local)
        U pa1 = {{r46[0], r57[0], r46[1], r57[1]}};   // keys 16..31

        // ---- PV: O[q][ch] ----
        __builtin_amdgcn_s_setprio(1);
        o0 = __builtin_amdgcn_mfma_f32_32x32x16_bf16(pa0.v, *(const bf16x8*)&vs[vboff[0][0]], o0, 0, 0, 0);
        o0 = __builtin_amdgcn_mfma_f32_32x32x16_bf16(pa1.v, *(const bf16x8*)&vs[vboff[0][1]], o0, 0, 0, 0);
        o1 = __builtin_amdgcn_mfma_f32_32x32x16_bf16(pa0.v, *(const bf16x8*)&vs[vboff[1][0]], o1, 0, 0, 0);
        o1 = __builtin_amdgcn_mfma_f32_32x32x16_bf16(pa1.v, *(const bf16x8*)&vs[vboff[1][1]], o1, 0, 0, 0);
        __builtin_amdgcn_s_setprio(0);

        // ---- pipeline: write next tile, barrier, issue loads for t+2 ----
        if (t < NT - 1) {
            *(uint4*)&kd[se0] = ka;  *(uint4*)&kd[se1] = kb;
            *(uint4*)&vd[se0] = va;  *(uint4*)&vd[se1] = vb;
        }
        __syncthreads();
        if (t < NT - 2) {
            int kt = kt0 + t + 2;
            ka = *(const uint4*)(Kbase + (size_t)kt * 8192);
            kb = *(const uint4*)(Kbase + (size_t)kt * 8192 + 16);
            va = *(const uint4*)(Vbase + kt * 128);
            vb = *(const uint4*)(Vbase + kt * 128 + 16);
        }
    };
    for (int tt = 0; tt < NT; tt += 2) { body(tt, 0); body(tt + 1, 1); }

    // ---- epilogue: reduce the two key-half waves, write partial O + l ----
    float* red = (float*)smem;          // [2][64][34] floats (17.4 KB)
    u16* ost = smem + 10240;            // [64][64] u16 (8 KB, disjoint from red)
    if (kh == 1) {
        float* dst = red + (qh * 64 + lane) * 34;
        #pragma unroll
        for (int r = 0; r < 16; r++) { dst[r] = o0[r]; dst[16 + r] = o1[r]; }
        dst[32] = lsum;
    }
    __syncthreads();
    if (kh == 0) {
        const float* src = red + (qh * 64 + lane) * 34;
        float l2 = lsum + src[32];
        i32x2 rr = __builtin_amdgcn_permlane32_swap(__float_as_int(l2), __float_as_int(l2), false, false);
        float lpart = __int_as_float(lh ? rr[0] : rr[1]);
        float lfull = l2 + lpart;
        #pragma unroll
        for (int r = 0; r < 16; r++) {
            float v0 = o0[r] + src[r];
            float v1 = o1[r] + src[16 + r];
            int ql = qh * 32 + (r & 3) + 8 * (r >> 2) + 4 * lh;
            ost[ql * 64 + l31] = f2bf(v0);
            ost[ql * 64 + 32 + l31] = f2bf(v1);
        }
        if (lane < 32)
            ml[(size_t)sp * 16384 + b * N_ + qt * 64 + qh * 32 + l31] = lfull;
    }
    __syncthreads();
    uint4* op = (uint4*)(Opart + (size_t)sp * 1048576 + ((size_t)(b * N_ + qt * 64)) * 64);
    const uint4* os4 = (const uint4*)ost;
    op[tid] = os4[tid];
    op[tid + 256] = os4[tid + 256];
}

// ---------------- Kernel 4: fused combine + output projection + residual ----------------
__global__ __launch_bounds__(256) void proj_kernel(
    const u16* __restrict__ Opart, const float* __restrict__ ml,
    const float* __restrict__ Wp, const float* __restrict__ bp,
    const float* __restrict__ x, float* __restrict__ out, int nsplit) {
    __shared__ __align__(16) u16 wp[64][64];
    __shared__ __align__(16) u16 og[64][64];
    const int b = blockIdx.x >> 6;
    const int nt = blockIdx.x & 63;
    const int tid = threadIdx.x;

    {   // stage Wp bf16 swizzled
        const int rw = tid >> 2, qd = tid & 3;
        const float4* wsrc = (const float4*)(Wp + rw * 64 + qd * 16);
        float4 f0 = wsrc[0], f1 = wsrc[1], f2 = wsrc[2], f3 = wsrc[3];
        u16 pk[16];
        pk[0]=f2bf(f0.x); pk[1]=f2bf(f0.y); pk[2]=f2bf(f0.z); pk[3]=f2bf(f0.w);
        pk[4]=f2bf(f1.x); pk[5]=f2bf(f1.y); pk[6]=f2bf(f1.z); pk[7]=f2bf(f1.w);
        pk[8]=f2bf(f2.x); pk[9]=f2bf(f2.y); pk[10]=f2bf(f2.z); pk[11]=f2bf(f2.w);
        pk[12]=f2bf(f3.x); pk[13]=f2bf(f3.y); pk[14]=f2bf(f3.z); pk[15]=f2bf(f3.w);
        int blk0 = (2 * qd) ^ (rw & 7), blk1 = (2 * qd + 1) ^ (rw & 7);
        *(uint4*)&wp[rw][blk0 * 8] = *(uint4*)&pk[0];
        *(uint4*)&wp[rw][blk1 * 8] = *(uint4*)&pk[8];
    }
    {   // stage O tile: combine nsplit partials, normalize by sum of l
        #pragma unroll
        for (int k2 = 0; k2 < 2; k2++) {
            int cidx = tid + k2 * 256;
            int px = cidx >> 3, blk = cidx & 7;
            int gpix = b * N_ + nt * 64 + px;
            float lsum = 0.f;
            for (int s = 0; s < nsplit; s++) lsum += ml[(size_t)s * 16384 + gpix];
            float inv = 1.f / lsum;
            float acc8[8] = {0.f,0.f,0.f,0.f,0.f,0.f,0.f,0.f};
            for (int s = 0; s < nsplit; s++) {
                u16 ov[8];
                *(uint4*)ov = *(const uint4*)(Opart + (size_t)s * 1048576 + (size_t)gpix * 64 + blk * 8);
                #pragma unroll
                for (int j = 0; j < 8; j++) acc8[j] += bf2f(ov[j]);
            }
            u16 y[8];
            #pragma unroll
            for (int j = 0; j < 8; j++) y[j] = f2bf(acc8[j] * inv);
            *(uint4*)&og[px][(blk ^ (px & 7)) * 8] = *(uint4*)y;
        }
    }
    __syncthreads();

    const int lane = tid & 63, w = tid >> 6;
    const int lr = lane & 15, lg = lane >> 4;
    const f32x4 zz = {0.f, 0.f, 0.f, 0.f};
    const int sa0 = (lg ^ (lr & 7)) * 8, sa1 = ((4 | lg) ^ (lr & 7)) * 8;

    bf16x8 a0 = *(const bf16x8*)&wp[w * 16 + lr][sa0];
    bf16x8 a1 = *(const bf16x8*)&wp[w * 16 + lr][sa1];
    float bias[4];
    #pragma unroll
    for (int r = 0; r < 4; r++) bias[r] = bp[w * 16 + lg * 4 + r];

    #pragma unroll
    for (int pt = 0; pt < 4; pt++) {
        bf16x8 b0 = *(const bf16x8*)&og[pt * 16 + lr][sa0];
        bf16x8 b1 = *(const bf16x8*)&og[pt * 16 + lr][sa1];
        f32x4 acc = __builtin_amdgcn_mfma_f32_16x16x32_bf16(a0, b0, zz, 0, 0, 0);
        acc = __builtin_amdgcn_mfma_f32_16x16x32_bf16(a1, b1, acc, 0, 0, 0);
        #pragma unroll
        for (int r = 0; r < 4; r++) {
            int cout = w * 16 + lg * 4 + r;
            int px = pt * 16 + lr;
            size_t idx = ((size_t)(b * 64 + cout)) * N_ + nt * 64 + px;
            out[idx] = x[idx] + bias[r] + acc[r];
        }
    }
}

extern "C" void kernel_launch(void* const* d_in, const int* in_sizes, int n_in,
                              void* d_out, int out_size, void* d_ws, size_t ws_size,
                              hipStream_t stream) {
    const float* x     = (const float*)d_in[0];
    const float* gamma = (const float*)d_in[1];
    const float* beta  = (const float*)d_in[2];
    const float* Wq    = (const float*)d_in[3];
    const float* bq    = (const float*)d_in[4];
    const float* Wk    = (const float*)d_in[5];
    const float* bk    = (const float*)d_in[6];
    const float* Wv    = (const float*)d_in[7];
    const float* bv    = (const float*)d_in[8];
    const float* Wp    = (const float*)d_in[9];
    const float* bp    = (const float*)d_in[10];
    float* out = (float*)d_out;

    const size_t elems = (size_t)B_ * N_ * C_;           // 1M
    // layout: partials 4KB | ml 256KB | Qb 2MB | Kb 2MB | Vt 2MB | Opart nsplit*2MB
    const size_t base = 4096 + 262144;
    float* partials = (float*)d_ws;
    float* ml = (float*)((char*)d_ws + 4096);
    u16* Qb = (u16*)((char*)d_ws + base);
    u16* Kb = Qb + elems;
    u16* Vt = Kb + elems;
    u16* Opart = Vt + elems;

    const size_t need4 = base + 3 * elems * 2 + 4 * elems * 2;
    const size_t need3 = base + 3 * elems * 2 + 3 * elems * 2;
    const int nsplit = (ws_size >= need4) ? 4 : (ws_size >= need3) ? 3 : 2;

    gn_reduce<<<256, 256, 0, stream>>>(x, partials);
    qkv_kernel<<<256, 256, 0, stream>>>(x, gamma, beta, partials,
                                        Wq, bq, Wk, bk, Wv, bv, Qb, Kb, Vt);
    flash_kernel<<<nsplit * 256, 256, 0, stream>>>(Qb, Kb, Vt, Opart, ml, nsplit);
    proj_kernel<<<256, 256, 0, stream>>>(Opart, ml, Wp, bp, x, out, nsplit);
}